// Round 9
// baseline (82.511 us; speedup 1.0000x reference)
//
#include <hip/hip_runtime.h>
#include <math.h>

#define B_IMG 16
#define P_N   2048
#define IMG_TM_U32 69632   // per-image padded triangular mask u32 words

constexpr float SCORE_T = 0.05f;
constexpr float XCLIP   = 4.135166556742356f; // log(1000/16)
constexpr float IMW     = 1333.0f;
constexpr float IMH     = 800.0f;

// monotone float->uint mapping (ascending float order, incl +inf)
__device__ __forceinline__ unsigned int fkey(float f) {
    unsigned int u = __float_as_uint(f);
    return (u & 0x80000000u) ? ~u : (u | 0x80000000u);
}

// Padded triangular layout: block b rows have RW(b)=4*((b>>1)+1) u32 words,
// 16B-aligned. Block start S(b) = 256*T(b), T(b) = (b&1)?(q+1)^2 : q(q+1).
__device__ __forceinline__ unsigned int row_base(int j) {
    int b = j >> 6, r = j & 63;
    int q = b >> 1;
    int T = (b & 1) ? (q + 1) * (q + 1) : q * (q + 1);
    int RW = 4 * (q + 1);
    return 256u * (unsigned)T + (unsigned)(r * RW);
}

__device__ __forceinline__ void decode_row(
    const float* cls, const float* codes, const float* props, int gid,
    float4& box, float& score)
{
    float2 lg = reinterpret_cast<const float2*>(cls)[gid];
    score = 1.0f / (1.0f + expf(lg.x - lg.y));
    float4 pb = reinterpret_cast<const float4*>(props)[gid];
    float4 c  = reinterpret_cast<const float4*>(codes)[gid * 2 + 1];
    float w  = pb.z - pb.x + 1.0f;
    float h  = pb.w - pb.y + 1.0f;
    float cx = pb.x + 0.5f * w;
    float cy = pb.y + 0.5f * h;
    float dx = c.x / 10.0f;
    float dy = c.y / 10.0f;
    float dw = fminf(c.z / 5.0f, XCLIP);
    float dh = fminf(c.w / 5.0f, XCLIP);
    float pcx = dx * w + cx;
    float pcy = dy * h + cy;
    float pw  = expf(dw) * w;
    float ph  = expf(dh) * h;
    float x1 = pcx - 0.5f * pw;
    float y1 = pcy - 0.5f * ph;
    float x2 = (pcx + 0.5f * pw) - 1.0f;
    float y2 = (pcy + 0.5f * ph) - 1.0f;
    box.x = fminf(fmaxf(x1, 0.0f), IMW - 1.0f);
    box.y = fminf(fmaxf(y1, 0.0f), IMH - 1.0f);
    box.z = fminf(fmaxf(x2, 0.0f), IMW - 1.0f);
    box.w = fminf(fmaxf(y2, 0.0f), IMH - 1.0f);
}

// ---------------------------------------------------------------------------
// K1: fused key-gen + stable rank-by-counting + decode + scatter sorted rows
// ---------------------------------------------------------------------------
__global__ __launch_bounds__(512) void rank_kernel(
    const float* __restrict__ cls, const float* __restrict__ codes,
    const float* __restrict__ props, float* __restrict__ out)
{
#pragma clang fp contract(off)
    __shared__ unsigned int sk[P_N];
    __shared__ unsigned short pc[512];
    const int img = blockIdx.x >> 5;   // 32 blocks per image
    const int blk = blockIdx.x & 31;   // 64 rows per block
    const int tid = threadIdx.x;

    for (int p = tid; p < P_N; p += 512) {
        float2 lg = reinterpret_cast<const float2*>(cls)[img * P_N + p];
        float score = 1.0f / (1.0f + expf(lg.x - lg.y));
        float keyf = (score > SCORE_T) ? -score : __int_as_float(0x7f800000);
        sk[p] = fkey(keyf);
    }
    __syncthreads();

    const int il = tid >> 3, sub = tid & 7;      // 8 threads per row
    const int i  = blk * 64 + il;
    const unsigned int ki = sk[i];
    int cnt = 0;
    for (int t = 0; t < 256; ++t) {
        int j = sub + 8 * ((t + il) & 255);
        unsigned int kj = sk[j];
        cnt += (kj < ki) || (kj == ki && j < i);
    }
    pc[tid] = (unsigned short)cnt;
    __syncthreads();

    if (tid < 64) {
        const int i2 = blk * 64 + tid;
        int r = 0;
#pragma unroll
        for (int s = 0; s < 8; ++s) r += pc[tid * 8 + s];
        float4 b; float sc;
        decode_row(cls, codes, props, img * P_N + i2, b, sc);
        float* o = out + ((size_t)img * P_N + r) * 5;
        o[0] = b.x; o[1] = b.y; o[2] = b.z; o[3] = b.w; o[4] = sc;
    }
}

// ---------------------------------------------------------------------------
// K2: triangular mask, tile-transposed, TWO i-blocks per wave.
//   Wave (img, g, c2): lane = j in block g; i-blocks c0=2*c2, c1=c0+1.
//   Exact no-division predicate (RN(inter/denom)>0.5 <=> inter>denom*C,
//   C=0.5*(1+2^-24), product exact in double; denom<=0 handled explicitly).
//   Stores one aligned uint4 (words 4*c2..4*c2+3) when both blocks present.
// ---------------------------------------------------------------------------
#define TM_WPB 4     // waves per block
#define TM_PPI 272   // tile-pairs per image = sum_{g=0}^{31} ((g+2)>>1)
__global__ __launch_bounds__(64 * TM_WPB) void tmask_kernel(
    const float* __restrict__ out, unsigned int* __restrict__ tmask)
{
#pragma clang fp contract(off)
    __shared__ float4 sbox[TM_WPB][128];
    __shared__ float  sarea[TM_WPB][128];
    const int tid  = threadIdx.x;
    const int wv   = tid >> 6;
    const int lane = tid & 63;

    const int W   = blockIdx.x * TM_WPB + wv;   // global wave id
    const int img = W / TM_PPI;
    int r = W - img * TM_PPI;
    int g = 0, acc = 0;
    while (acc + ((g + 2) >> 1) <= r) { acc += (g + 2) >> 1; ++g; }
    const int c2 = r - acc;
    const int c0 = 2 * c2, c1 = c0 + 1;

    // stage i-blocks c0 and c1 (c1 row always in-bounds; content unused if c1>g)
    {
        const int i0 = c0 * 64 + lane;
        const float* oi = out + ((size_t)img * P_N + i0) * 5;
        float4 bi = make_float4(oi[0], oi[1], oi[2], oi[3]);
        sbox[wv][lane]  = bi;
        sarea[wv][lane] = (bi.z - bi.x) * (bi.w - bi.y);
        const float* oj2 = oi + 64 * 5;
        float4 b2 = make_float4(oj2[0], oj2[1], oj2[2], oj2[3]);
        sbox[wv][64 + lane]  = b2;
        sarea[wv][64 + lane] = (b2.z - b2.x) * (b2.w - b2.y);
    }
    // per-lane j row
    const int jrow = g * 64 + lane;
    const float* oj = out + ((size_t)img * P_N + jrow) * 5;
    const float4 bj = make_float4(oj[0], oj[1], oj[2], oj[3]);
    const float  aj = (bj.z - bj.x) * (bj.w - bj.y);
    __syncthreads();

    const double C = 0x1.000001p-1;   // 0.5*(1+2^-24)
    unsigned int w0 = 0, w1 = 0, w2 = 0, w3 = 0;

#define IOU_SUP(IDX, SUP)                                                    \
    bool SUP;                                                                \
    {                                                                        \
        float4 bi = sbox[wv][(IDX)];                                         \
        float  ai = sarea[wv][(IDX)];                                        \
        float ltx = fmaxf(bi.x, bj.x);                                       \
        float lty = fmaxf(bi.y, bj.y);                                       \
        float rbx = fminf(bi.z, bj.z);                                       \
        float rby = fminf(bi.w, bj.w);                                       \
        float wx = fmaxf(rbx - ltx, 0.0f);                                   \
        float wy = fmaxf(rby - lty, 0.0f);                                   \
        float inter = wx * wy;                                               \
        float denom = ((ai + aj) - inter) + 1e-9f;                           \
        SUP = ((double)inter > (double)denom * C);                           \
        if (!(denom > 0.0f))                                                 \
            SUP = (inter > 0.0f) && (__float_as_uint(denom) == 0u);          \
    }

    if (c1 < g) {            // two plain i-blocks
#pragma unroll 8
        for (int t = 0; t < 32; ++t) {
            IOU_SUP(t,        sa) w0 |= (unsigned int)sa << t;
            IOU_SUP(t + 32,   sb) w1 |= (unsigned int)sb << t;
            IOU_SUP(t + 64,   sc) w2 |= (unsigned int)sc << t;
            IOU_SUP(t + 96,   sd) w3 |= (unsigned int)sd << t;
        }
    } else if (c1 == g) {    // second block is the diagonal
#pragma unroll 8
        for (int t = 0; t < 32; ++t) {
            IOU_SUP(t,        sa) w0 |= (unsigned int)sa << t;
            IOU_SUP(t + 32,   sb) w1 |= (unsigned int)sb << t;
            IOU_SUP(t + 64,   sc) w2 |= (unsigned int)(sc && (t      < lane)) << t;
            IOU_SUP(t + 96,   sd) w3 |= (unsigned int)(sd && (t + 32 < lane)) << t;
        }
    } else {                 // c0 == g: single diagonal block
#pragma unroll 8
        for (int t = 0; t < 32; ++t) {
            IOU_SUP(t,        sa) w0 |= (unsigned int)(sa && (t      < lane)) << t;
            IOU_SUP(t + 32,   sb) w1 |= (unsigned int)(sb && (t + 32 < lane)) << t;
        }
    }
#undef IOU_SUP

    unsigned int* dst = tmask + (size_t)img * IMG_TM_U32 + row_base(jrow) + 4 * c2;
    if (c1 <= g) {
        *reinterpret_cast<uint4*>(dst) = make_uint4(w0, w1, w2, w3);
    } else {
        *reinterpret_cast<uint2*>(dst) = make_uint2(w0, w1);
    }
}

// ---------------------------------------------------------------------------
// K3: Jacobi fixpoint, register-exact (validated round 8). 1024 thr/image,
//   2 rows/thread, pairing (g, 31-g): exactly 17 uint4 of mask per thread.
// ---------------------------------------------------------------------------
template<int G>
struct RowMask {
    static constexpr int Q  = G >> 1;
    static constexpr int NV = Q + 1;                 // uint4 count = RW/4
    static constexpr int NW = 2 * (G + 1);           // valid words
    static constexpr int RW = 4 * NV;
    static constexpr int TT = (G & 1) ? (Q + 1) * (Q + 1) : Q * (Q + 1);
    static constexpr int S  = 256 * TT;              // block start (words)
    uint4 m[NV];
    __device__ __forceinline__ void load(const unsigned int* tmi, int lane) {
        const uint4* p = reinterpret_cast<const uint4*>(tmi + S + lane * RW);
#pragma unroll
        for (int v = 0; v < NV; ++v) m[v] = p[v];
        if constexpr (NW < RW) {   // even G: padding words never written
            m[NV - 1].z = 0u; m[NV - 1].w = 0u;
        }
    }
    __device__ __forceinline__ unsigned int andor(const unsigned int* kw) const {
        const uint4* kw4 = reinterpret_cast<const uint4*>(kw);
        unsigned int s = 0;
#pragma unroll
        for (int v = 0; v < NV; ++v) {
            uint4 K = kw4[v];
            s |= m[v].x & K.x;
            s |= m[v].y & K.y;
            s |= m[v].z & K.z;
            s |= m[v].w & K.w;
        }
        return s;
    }
};

template<int G1, int G2>
__device__ __forceinline__ void fp_body(
    float* __restrict__ out, const unsigned int* __restrict__ tmi,
    int img, int lane, unsigned int* kw, int* flag)
{
    RowMask<G1> M1; RowMask<G2> M2;
    M1.load(tmi, lane);
    M2.load(tmi, lane);
    const int j1 = G1 * 64 + lane, j2 = G2 * 64 + lane;
    const bool v1 = out[((size_t)img * P_N + j1) * 5 + 4] > SCORE_T;
    const bool v2 = out[((size_t)img * P_N + j2) * 5 + 4] > SCORE_T;
    bool k1 = v1, k2 = v2;

    auto publish = [&](bool a, bool b) {
        unsigned long long t = __ballot(a);
        if (lane == 0) { kw[2*G1] = (unsigned int)t; kw[2*G1+1] = (unsigned int)(t >> 32); }
        t = __ballot(b);
        if (lane == 0) { kw[2*G2] = (unsigned int)t; kw[2*G2+1] = (unsigned int)(t >> 32); }
    };

    publish(k1, k2);
    __syncthreads();

    for (;;) {
        unsigned int s1 = M1.andor(kw);
        unsigned int s2 = M2.andor(kw);
        bool nk1 = v1 && (s1 == 0u);
        bool nk2 = v2 && (s2 == 0u);
        bool ch = (nk1 != k1) | (nk2 != k2);
        __syncthreads();                 // (1) kw reads done
        if constexpr (G1 == 0) { if (lane == 0) *flag = 0; }
        __syncthreads();                 // (2) reset visible
        publish(nk1, nk2);
        if (__builtin_amdgcn_ballot_w64(ch) != 0 && lane == 0) *flag = 1;
        k1 = nk1; k2 = nk2;
        __syncthreads();                 // (3) new kw + flag visible
        if (!*flag) break;
    }

    if (!k1) { float* o = out + ((size_t)img * P_N + j1) * 5;
        o[0] = 0.0f; o[1] = 0.0f; o[2] = 0.0f; o[3] = 0.0f; o[4] = 0.0f; }
    if (!k2) { float* o = out + ((size_t)img * P_N + j2) * 5;
        o[0] = 0.0f; o[1] = 0.0f; o[2] = 0.0f; o[3] = 0.0f; o[4] = 0.0f; }
}

__global__ __launch_bounds__(1024) void fixpoint_kernel(
    float* __restrict__ out, const unsigned int* __restrict__ tmask)
{
    __shared__ __align__(16) unsigned int kw[64];
    __shared__ int flag;
    const int img = blockIdx.x, tid = threadIdx.x;
    const int wv = tid >> 6, lane = tid & 63;
    const unsigned int* tmi = tmask + (size_t)img * IMG_TM_U32;
    switch (wv) {
        case  0: fp_body< 0, 31>(out, tmi, img, lane, kw, &flag); break;
        case  1: fp_body< 1, 30>(out, tmi, img, lane, kw, &flag); break;
        case  2: fp_body< 2, 29>(out, tmi, img, lane, kw, &flag); break;
        case  3: fp_body< 3, 28>(out, tmi, img, lane, kw, &flag); break;
        case  4: fp_body< 4, 27>(out, tmi, img, lane, kw, &flag); break;
        case  5: fp_body< 5, 26>(out, tmi, img, lane, kw, &flag); break;
        case  6: fp_body< 6, 25>(out, tmi, img, lane, kw, &flag); break;
        case  7: fp_body< 7, 24>(out, tmi, img, lane, kw, &flag); break;
        case  8: fp_body< 8, 23>(out, tmi, img, lane, kw, &flag); break;
        case  9: fp_body< 9, 22>(out, tmi, img, lane, kw, &flag); break;
        case 10: fp_body<10, 21>(out, tmi, img, lane, kw, &flag); break;
        case 11: fp_body<11, 20>(out, tmi, img, lane, kw, &flag); break;
        case 12: fp_body<12, 19>(out, tmi, img, lane, kw, &flag); break;
        case 13: fp_body<13, 18>(out, tmi, img, lane, kw, &flag); break;
        case 14: fp_body<14, 17>(out, tmi, img, lane, kw, &flag); break;
        case 15: fp_body<15, 16>(out, tmi, img, lane, kw, &flag); break;
    }
}

// ---------------------------------------------------------------------------
// ws-too-small fallback (validated rounds 1-4): bitonic sort + serial cascade
// ---------------------------------------------------------------------------
__global__ __launch_bounds__(1024) void prep_sort_kernel(
    const float* __restrict__ cls, const float* __restrict__ codes,
    const float* __restrict__ props, float* __restrict__ out)
{
#pragma clang fp contract(off)
    __shared__ float4 sbox[P_N];
    __shared__ float  ssc[P_N];
    __shared__ unsigned long long skey[P_N];
    const int img = blockIdx.x;
    const int tid = threadIdx.x;

    for (int p = tid; p < P_N; p += 1024) {
        float4 b; float sc;
        decode_row(cls, codes, props, img * P_N + p, b, sc);
        sbox[p] = b;
        ssc[p]  = sc;
        float key = (sc > SCORE_T) ? -sc : __int_as_float(0x7f800000);
        skey[p] = (((unsigned long long)fkey(key)) << 32) | (unsigned int)p;
    }
    __syncthreads();
    for (int k = 2; k <= P_N; k <<= 1) {
        for (int j = k >> 1; j > 0; j >>= 1) {
            for (int t = tid; t < P_N; t += 1024) {
                int ixj = t ^ j;
                if (ixj > t) {
                    unsigned long long a = skey[t], b = skey[ixj];
                    bool up = ((t & k) == 0);
                    if ((a > b) == up) { skey[t] = b; skey[ixj] = a; }
                }
            }
            __syncthreads();
        }
    }
    for (int e = tid; e < P_N; e += 1024) {
        unsigned long long kv = skey[e];
        int idx = (int)(kv & 0xFFFFFFFFull);
        float4 b4 = sbox[idx];
        float  s  = ssc[idx];
        float* o = out + ((size_t)img * P_N + e) * 5;
        o[0] = b4.x; o[1] = b4.y; o[2] = b4.z; o[3] = b4.w; o[4] = s;
    }
}

__global__ __launch_bounds__(64) void nms_fallback(float* __restrict__ out)
{
#pragma clang fp contract(off)
    __shared__ float4 sb[P_N];
    const int img  = blockIdx.x;
    const int lane = threadIdx.x;
    unsigned int keep = 0;
    for (int b = 0; b < 32; ++b) {
        int p = lane * 32 + b;
        const float* o = out + ((size_t)img * P_N + p) * 5;
        sb[p] = make_float4(o[0], o[1], o[2], o[3]);
        if (o[4] > SCORE_T) keep |= (1u << b);
    }
    __syncthreads();
    for (int i = 0; i < P_N; ++i) {
        unsigned int kw =
            (unsigned int)__builtin_amdgcn_readlane((int)keep, i >> 5);
        if ((kw >> (i & 31)) & 1u) {
            float4 bi = sb[i];
            float area_i = (bi.z - bi.x) * (bi.w - bi.y);
            unsigned int m = 0;
            for (int b = 0; b < 32; ++b) {
                int j = lane * 32 + b;
                if (j > i) {
                    float4 bj = sb[j];
                    float area_j = (bj.z - bj.x) * (bj.w - bj.y);
                    float ltx = fmaxf(bi.x, bj.x);
                    float lty = fmaxf(bi.y, bj.y);
                    float rbx = fminf(bi.z, bj.z);
                    float rby = fminf(bi.w, bj.w);
                    float wx = fmaxf(rbx - ltx, 0.0f);
                    float wy = fmaxf(rby - lty, 0.0f);
                    float inter = wx * wy;
                    float denom = ((area_i + area_j) - inter) + 1e-9f;
                    if ((inter / denom) > 0.5f) m |= (1u << b);
                }
            }
            keep &= ~m;
        }
    }
    for (int b = 0; b < 32; ++b) {
        if (!((keep >> b) & 1u)) {
            int p = lane * 32 + b;
            float* o = out + ((size_t)img * P_N + p) * 5;
            o[0] = 0.0f; o[1] = 0.0f; o[2] = 0.0f; o[3] = 0.0f; o[4] = 0.0f;
        }
    }
}

// ---------------------------------------------------------------------------
extern "C" void kernel_launch(void* const* d_in, const int* in_sizes, int n_in,
                              void* d_out, int out_size, void* d_ws, size_t ws_size,
                              hipStream_t stream) {
    const float* cls   = (const float*)d_in[0];
    const float* codes = (const float*)d_in[1];
    const float* props = (const float*)d_in[2];
    float* out = (float*)d_out;

    const size_t tmask_bytes = (size_t)B_IMG * IMG_TM_U32 * 4;   // 4.46 MB

    if (ws_size >= tmask_bytes) {
        unsigned int* tmask = (unsigned int*)d_ws;
        rank_kernel<<<B_IMG * 32, 512, 0, stream>>>(cls, codes, props, out);
        tmask_kernel<<<(B_IMG * TM_PPI) / TM_WPB, 64 * TM_WPB, 0, stream>>>(out, tmask);
        fixpoint_kernel<<<B_IMG, 1024, 0, stream>>>(out, tmask);
    } else {
        prep_sort_kernel<<<B_IMG, 1024, 0, stream>>>(cls, codes, props, out);
        nms_fallback<<<B_IMG, 64, 0, stream>>>(out);
    }
}

// Round 12
// 78.743 us; speedup vs baseline: 1.0478x; 1.0478x over previous
//
#include <hip/hip_runtime.h>
#include <math.h>

#define B_IMG 16
#define P_N   2048
#define IMG_TM_U32 69632   // per-image padded triangular mask u32 words

constexpr float SCORE_T = 0.05f;
constexpr float XCLIP   = 4.135166556742356f; // log(1000/16)
constexpr float IMW     = 1333.0f;
constexpr float IMH     = 800.0f;

// monotone float->uint mapping (ascending float order, incl +inf)
__device__ __forceinline__ unsigned int fkey(float f) {
    unsigned int u = __float_as_uint(f);
    return (u & 0x80000000u) ? ~u : (u | 0x80000000u);
}

// Padded triangular layout: block b rows have RW(b)=4*((b>>1)+1) u32 words,
// 16B-aligned. Block start S(b) = 256*T(b), T(b) = (b&1)?(q+1)^2 : q(q+1).
__device__ __forceinline__ unsigned int row_base(int j) {
    int b = j >> 6, r = j & 63;
    int q = b >> 1;
    int T = (b & 1) ? (q + 1) * (q + 1) : q * (q + 1);
    int RW = 4 * (q + 1);
    return 256u * (unsigned)T + (unsigned)(r * RW);
}

__device__ __forceinline__ void decode_row(
    const float* cls, const float* codes, const float* props, int gid,
    float4& box, float& score)
{
    float2 lg = reinterpret_cast<const float2*>(cls)[gid];
    score = 1.0f / (1.0f + expf(lg.x - lg.y));
    float4 pb = reinterpret_cast<const float4*>(props)[gid];
    float4 c  = reinterpret_cast<const float4*>(codes)[gid * 2 + 1];
    float w  = pb.z - pb.x + 1.0f;
    float h  = pb.w - pb.y + 1.0f;
    float cx = pb.x + 0.5f * w;
    float cy = pb.y + 0.5f * h;
    float dx = c.x / 10.0f;
    float dy = c.y / 10.0f;
    float dw = fminf(c.z / 5.0f, XCLIP);
    float dh = fminf(c.w / 5.0f, XCLIP);
    float pcx = dx * w + cx;
    float pcy = dy * h + cy;
    float pw  = expf(dw) * w;
    float ph  = expf(dh) * h;
    float x1 = pcx - 0.5f * pw;
    float y1 = pcy - 0.5f * ph;
    float x2 = (pcx + 0.5f * pw) - 1.0f;
    float y2 = (pcy + 0.5f * ph) - 1.0f;
    box.x = fminf(fmaxf(x1, 0.0f), IMW - 1.0f);
    box.y = fminf(fmaxf(y1, 0.0f), IMH - 1.0f);
    box.z = fminf(fmaxf(x2, 0.0f), IMW - 1.0f);
    box.w = fminf(fmaxf(y2, 0.0f), IMH - 1.0f);
}

// ---------------------------------------------------------------------------
// K1: fused key-gen + stable rank-by-counting + decode + scatter sorted rows
// ---------------------------------------------------------------------------
__global__ __launch_bounds__(512) void rank_kernel(
    const float* __restrict__ cls, const float* __restrict__ codes,
    const float* __restrict__ props, float* __restrict__ out)
{
#pragma clang fp contract(off)
    __shared__ unsigned int sk[P_N];
    __shared__ unsigned short pc[512];
    const int img = blockIdx.x >> 5;   // 32 blocks per image
    const int blk = blockIdx.x & 31;   // 64 rows per block
    const int tid = threadIdx.x;

    for (int p = tid; p < P_N; p += 512) {
        float2 lg = reinterpret_cast<const float2*>(cls)[img * P_N + p];
        float score = 1.0f / (1.0f + expf(lg.x - lg.y));
        float keyf = (score > SCORE_T) ? -score : __int_as_float(0x7f800000);
        sk[p] = fkey(keyf);
    }
    __syncthreads();

    const int il = tid >> 3, sub = tid & 7;      // 8 threads per row
    const int i  = blk * 64 + il;
    const unsigned int ki = sk[i];
    int cnt = 0;
    for (int t = 0; t < 256; ++t) {
        int j = sub + 8 * ((t + il) & 255);
        unsigned int kj = sk[j];
        cnt += (kj < ki) || (kj == ki && j < i);
    }
    pc[tid] = (unsigned short)cnt;
    __syncthreads();

    if (tid < 64) {
        const int i2 = blk * 64 + tid;
        int r = 0;
#pragma unroll
        for (int s = 0; s < 8; ++s) r += pc[tid * 8 + s];
        float4 b; float sc;
        decode_row(cls, codes, props, img * P_N + i2, b, sc);
        float* o = out + ((size_t)img * P_N + r) * 5;
        o[0] = b.x; o[1] = b.y; o[2] = b.z; o[3] = b.w; o[4] = sc;
    }
}

// ---------------------------------------------------------------------------
// K2: triangular mask, tile-transposed, ONE i-block per wave, NO LDS.
//   Each lane holds its i-box (row c*64+lane) in registers; the inner loop
//   broadcasts lane t's box via v_readlane (compile-time lane index).
//   Arithmetic is bit-identical to the round-8-validated LDS version
//   (same expression order, fp contract off; staging path changes no bits).
//   Predicate: VALIDATED double form (passed rounds 7-9, absmax 0):
//     RN(inter/denom) > 0.5  <=>  (double)inter > (double)denom * C,
//     C = 0.5*(1+2^-24) exact in f64; denom<=+-0 edge cases explicit.
// ---------------------------------------------------------------------------
#define TM_WPB 4     // waves per block
#define TM_TPI 528   // tiles per image = 32*33/2
__global__ __launch_bounds__(64 * TM_WPB) void tmask_kernel(
    const float* __restrict__ out, unsigned int* __restrict__ tmask)
{
#pragma clang fp contract(off)
    const int tid  = threadIdx.x;
    const int wv   = tid >> 6;
    const int lane = tid & 63;

    const int W   = blockIdx.x * TM_WPB + wv;   // global wave id
    const int img = W / TM_TPI;
    int r = W - img * TM_TPI;
    int g = 0, acc = 0;
    while (acc + g + 1 <= r) { acc += g + 1; ++g; }
    const int c = r - acc;                      // 0 <= c <= g

    // lane's i-row (block c) in registers
    const float* oi = out + ((size_t)img * P_N + c * 64 + lane) * 5;
    const float ix1 = oi[0], iy1 = oi[1], ix2 = oi[2], iy2 = oi[3];
    const float iar = (ix2 - ix1) * (iy2 - iy1);

    // lane's j-row (block g)
    const float* oj = out + ((size_t)img * P_N + g * 64 + lane) * 5;
    const float jx1 = oj[0], jy1 = oj[1], jx2 = oj[2], jy2 = oj[3];
    const float aj  = (jx2 - jx1) * (jy2 - jy1);

    const int tlim = (c < g) ? 64 : lane;   // diagonal tile: need i < j
    const double C = 0x1.000001p-1;         // 0.5*(1+2^-24), exact in f64
    unsigned int w0 = 0, w1 = 0;

#pragma unroll
    for (int t = 0; t < 64; ++t) {
        float bx1 = __int_as_float(__builtin_amdgcn_readlane(__float_as_int(ix1), t));
        float by1 = __int_as_float(__builtin_amdgcn_readlane(__float_as_int(iy1), t));
        float bx2 = __int_as_float(__builtin_amdgcn_readlane(__float_as_int(ix2), t));
        float by2 = __int_as_float(__builtin_amdgcn_readlane(__float_as_int(iy2), t));
        float ai  = __int_as_float(__builtin_amdgcn_readlane(__float_as_int(iar), t));
        float ltx = fmaxf(bx1, jx1);
        float lty = fmaxf(by1, jy1);
        float rbx = fminf(bx2, jx2);
        float rby = fminf(by2, jy2);
        float wx = fmaxf(rbx - ltx, 0.0f);
        float wy = fmaxf(rby - lty, 0.0f);
        float inter = wx * wy;
        float denom = ((ai + aj) - inter) + 1e-9f;
        bool sup = ((double)inter > (double)denom * C);
        if (!(denom > 0.0f))
            sup = (inter > 0.0f) && (__float_as_uint(denom) == 0u);
        sup = sup && (t < tlim);
        if (t < 32) w0 |= (unsigned int)sup << t;
        else        w1 |= (unsigned int)sup << (t - 32);
    }

    unsigned int* dst = tmask + (size_t)img * IMG_TM_U32
                      + row_base(g * 64 + lane) + 2 * c;
    *reinterpret_cast<uint2*>(dst) = make_uint2(w0, w1);
}

// ---------------------------------------------------------------------------
// K3: Jacobi fixpoint, register-exact masks. VERBATIM revert to the
//   3-barrier version validated in rounds 8 and 9 (the single-barrier
//   rewrite failed twice with identical absmax and is abandoned).
//   1024 thr/image, 2 rows/thread, pairing (g, 31-g): 17 uint4 mask/thread.
// ---------------------------------------------------------------------------
template<int G>
struct RowMask {
    static constexpr int Q  = G >> 1;
    static constexpr int NV = Q + 1;                 // uint4 count = RW/4
    static constexpr int NW = 2 * (G + 1);           // valid words
    static constexpr int RW = 4 * NV;
    static constexpr int TT = (G & 1) ? (Q + 1) * (Q + 1) : Q * (Q + 1);
    static constexpr int S  = 256 * TT;              // block start (words)
    uint4 m[NV];
    __device__ __forceinline__ void load(const unsigned int* tmi, int lane) {
        const uint4* p = reinterpret_cast<const uint4*>(tmi + S + lane * RW);
#pragma unroll
        for (int v = 0; v < NV; ++v) m[v] = p[v];
        if constexpr (NW < RW) {   // even G: padding words never written
            m[NV - 1].z = 0u; m[NV - 1].w = 0u;
        }
    }
    __device__ __forceinline__ unsigned int andor(const unsigned int* kw) const {
        const uint4* kw4 = reinterpret_cast<const uint4*>(kw);
        unsigned int s = 0;
#pragma unroll
        for (int v = 0; v < NV; ++v) {
            uint4 K = kw4[v];
            s |= m[v].x & K.x;
            s |= m[v].y & K.y;
            s |= m[v].z & K.z;
            s |= m[v].w & K.w;
        }
        return s;
    }
};

template<int G1, int G2>
__device__ __forceinline__ void fp_body(
    float* __restrict__ out, const unsigned int* __restrict__ tmi,
    int img, int lane, unsigned int* kw, int* flag)
{
    RowMask<G1> M1; RowMask<G2> M2;
    M1.load(tmi, lane);
    M2.load(tmi, lane);
    const int j1 = G1 * 64 + lane, j2 = G2 * 64 + lane;
    const bool v1 = out[((size_t)img * P_N + j1) * 5 + 4] > SCORE_T;
    const bool v2 = out[((size_t)img * P_N + j2) * 5 + 4] > SCORE_T;
    bool k1 = v1, k2 = v2;

    auto publish = [&](bool a, bool b) {
        unsigned long long t = __ballot(a);
        if (lane == 0) { kw[2*G1] = (unsigned int)t; kw[2*G1+1] = (unsigned int)(t >> 32); }
        t = __ballot(b);
        if (lane == 0) { kw[2*G2] = (unsigned int)t; kw[2*G2+1] = (unsigned int)(t >> 32); }
    };

    publish(k1, k2);
    __syncthreads();

    for (;;) {
        unsigned int s1 = M1.andor(kw);
        unsigned int s2 = M2.andor(kw);
        bool nk1 = v1 && (s1 == 0u);
        bool nk2 = v2 && (s2 == 0u);
        bool ch = (nk1 != k1) | (nk2 != k2);
        __syncthreads();                 // (1) all kw reads done
        if constexpr (G1 == 0) { if (lane == 0) *flag = 0; }
        __syncthreads();                 // (2) reset visible
        publish(nk1, nk2);
        if (__builtin_amdgcn_ballot_w64(ch) != 0 && lane == 0) *flag = 1;
        k1 = nk1; k2 = nk2;
        __syncthreads();                 // (3) new kw + flag visible
        if (!*flag) break;
    }

    if (!k1) { float* o = out + ((size_t)img * P_N + j1) * 5;
        o[0] = 0.0f; o[1] = 0.0f; o[2] = 0.0f; o[3] = 0.0f; o[4] = 0.0f; }
    if (!k2) { float* o = out + ((size_t)img * P_N + j2) * 5;
        o[0] = 0.0f; o[1] = 0.0f; o[2] = 0.0f; o[3] = 0.0f; o[4] = 0.0f; }
}

__global__ __launch_bounds__(1024) void fixpoint_kernel(
    float* __restrict__ out, const unsigned int* __restrict__ tmask)
{
    __shared__ __align__(16) unsigned int kw[64];
    __shared__ int flag;
    const int img = blockIdx.x, tid = threadIdx.x;
    const int wv = tid >> 6, lane = tid & 63;
    const unsigned int* tmi = tmask + (size_t)img * IMG_TM_U32;
    switch (wv) {
        case  0: fp_body< 0, 31>(out, tmi, img, lane, kw, &flag); break;
        case  1: fp_body< 1, 30>(out, tmi, img, lane, kw, &flag); break;
        case  2: fp_body< 2, 29>(out, tmi, img, lane, kw, &flag); break;
        case  3: fp_body< 3, 28>(out, tmi, img, lane, kw, &flag); break;
        case  4: fp_body< 4, 27>(out, tmi, img, lane, kw, &flag); break;
        case  5: fp_body< 5, 26>(out, tmi, img, lane, kw, &flag); break;
        case  6: fp_body< 6, 25>(out, tmi, img, lane, kw, &flag); break;
        case  7: fp_body< 7, 24>(out, tmi, img, lane, kw, &flag); break;
        case  8: fp_body< 8, 23>(out, tmi, img, lane, kw, &flag); break;
        case  9: fp_body< 9, 22>(out, tmi, img, lane, kw, &flag); break;
        case 10: fp_body<10, 21>(out, tmi, img, lane, kw, &flag); break;
        case 11: fp_body<11, 20>(out, tmi, img, lane, kw, &flag); break;
        case 12: fp_body<12, 19>(out, tmi, img, lane, kw, &flag); break;
        case 13: fp_body<13, 18>(out, tmi, img, lane, kw, &flag); break;
        case 14: fp_body<14, 17>(out, tmi, img, lane, kw, &flag); break;
        case 15: fp_body<15, 16>(out, tmi, img, lane, kw, &flag); break;
    }
}

// ---------------------------------------------------------------------------
// ws-too-small fallback (validated rounds 1-4): bitonic sort + serial cascade
// ---------------------------------------------------------------------------
__global__ __launch_bounds__(1024) void prep_sort_kernel(
    const float* __restrict__ cls, const float* __restrict__ codes,
    const float* __restrict__ props, float* __restrict__ out)
{
#pragma clang fp contract(off)
    __shared__ float4 sbox[P_N];
    __shared__ float  ssc[P_N];
    __shared__ unsigned long long skey[P_N];
    const int img = blockIdx.x;
    const int tid = threadIdx.x;

    for (int p = tid; p < P_N; p += 1024) {
        float4 b; float sc;
        decode_row(cls, codes, props, img * P_N + p, b, sc);
        sbox[p] = b;
        ssc[p]  = sc;
        float key = (sc > SCORE_T) ? -sc : __int_as_float(0x7f800000);
        skey[p] = (((unsigned long long)fkey(key)) << 32) | (unsigned int)p;
    }
    __syncthreads();
    for (int k = 2; k <= P_N; k <<= 1) {
        for (int j = k >> 1; j > 0; j >>= 1) {
            for (int t = tid; t < P_N; t += 1024) {
                int ixj = t ^ j;
                if (ixj > t) {
                    unsigned long long a = skey[t], b = skey[ixj];
                    bool up = ((t & k) == 0);
                    if ((a > b) == up) { skey[t] = b; skey[ixj] = a; }
                }
            }
            __syncthreads();
        }
    }
    for (int e = tid; e < P_N; e += 1024) {
        unsigned long long kv = skey[e];
        int idx = (int)(kv & 0xFFFFFFFFull);
        float4 b4 = sbox[idx];
        float  s  = ssc[idx];
        float* o = out + ((size_t)img * P_N + e) * 5;
        o[0] = b4.x; o[1] = b4.y; o[2] = b4.z; o[3] = b4.w; o[4] = s;
    }
}

__global__ __launch_bounds__(64) void nms_fallback(float* __restrict__ out)
{
#pragma clang fp contract(off)
    __shared__ float4 sb[P_N];
    const int img  = blockIdx.x;
    const int lane = threadIdx.x;
    unsigned int keep = 0;
    for (int b = 0; b < 32; ++b) {
        int p = lane * 32 + b;
        const float* o = out + ((size_t)img * P_N + p) * 5;
        sb[p] = make_float4(o[0], o[1], o[2], o[3]);
        if (o[4] > SCORE_T) keep |= (1u << b);
    }
    __syncthreads();
    for (int i = 0; i < P_N; ++i) {
        unsigned int kw =
            (unsigned int)__builtin_amdgcn_readlane((int)keep, i >> 5);
        if ((kw >> (i & 31)) & 1u) {
            float4 bi = sb[i];
            float area_i = (bi.z - bi.x) * (bi.w - bi.y);
            unsigned int m = 0;
            for (int b = 0; b < 32; ++b) {
                int j = lane * 32 + b;
                if (j > i) {
                    float4 bj = sb[j];
                    float area_j = (bj.z - bj.x) * (bj.w - bj.y);
                    float ltx = fmaxf(bi.x, bj.x);
                    float lty = fmaxf(bi.y, bj.y);
                    float rbx = fminf(bi.z, bj.z);
                    float rby = fminf(bi.w, bj.w);
                    float wx = fmaxf(rbx - ltx, 0.0f);
                    float wy = fmaxf(rby - lty, 0.0f);
                    float inter = wx * wy;
                    float denom = ((area_i + area_j) - inter) + 1e-9f;
                    if ((inter / denom) > 0.5f) m |= (1u << b);
                }
            }
            keep &= ~m;
        }
    }
    for (int b = 0; b < 32; ++b) {
        if (!((keep >> b) & 1u)) {
            int p = lane * 32 + b;
            float* o = out + ((size_t)img * P_N + p) * 5;
            o[0] = 0.0f; o[1] = 0.0f; o[2] = 0.0f; o[3] = 0.0f; o[4] = 0.0f;
        }
    }
}

// ---------------------------------------------------------------------------
extern "C" void kernel_launch(void* const* d_in, const int* in_sizes, int n_in,
                              void* d_out, int out_size, void* d_ws, size_t ws_size,
                              hipStream_t stream) {
    const float* cls   = (const float*)d_in[0];
    const float* codes = (const float*)d_in[1];
    const float* props = (const float*)d_in[2];
    float* out = (float*)d_out;

    const size_t tmask_bytes = (size_t)B_IMG * IMG_TM_U32 * 4;   // 4.46 MB

    if (ws_size >= tmask_bytes) {
        unsigned int* tmask = (unsigned int*)d_ws;
        rank_kernel<<<B_IMG * 32, 512, 0, stream>>>(cls, codes, props, out);
        tmask_kernel<<<(B_IMG * TM_TPI) / TM_WPB, 64 * TM_WPB, 0, stream>>>(out, tmask);
        fixpoint_kernel<<<B_IMG, 1024, 0, stream>>>(out, tmask);
    } else {
        prep_sort_kernel<<<B_IMG, 1024, 0, stream>>>(cls, codes, props, out);
        nms_fallback<<<B_IMG, 64, 0, stream>>>(out);
    }
}

// Round 13
// 78.161 us; speedup vs baseline: 1.0557x; 1.0074x over previous
//
#include <hip/hip_runtime.h>
#include <math.h>

#define B_IMG 16
#define P_N   2048
#define IMG_TM_U32 69632   // per-image padded triangular mask u32 words

constexpr float SCORE_T = 0.05f;
constexpr float XCLIP   = 4.135166556742356f; // log(1000/16)
constexpr float IMW     = 1333.0f;
constexpr float IMH     = 800.0f;

// monotone float->uint mapping (ascending float order, incl +inf)
__device__ __forceinline__ unsigned int fkey(float f) {
    unsigned int u = __float_as_uint(f);
    return (u & 0x80000000u) ? ~u : (u | 0x80000000u);
}

// Padded triangular layout: block b rows have RW(b)=4*((b>>1)+1) u32 words,
// 16B-aligned. Block start S(b) = 256*T(b), T(b) = (b&1)?(q+1)^2 : q(q+1).
__device__ __forceinline__ unsigned int row_base(int j) {
    int b = j >> 6, r = j & 63;
    int q = b >> 1;
    int T = (b & 1) ? (q + 1) * (q + 1) : q * (q + 1);
    int RW = 4 * (q + 1);
    return 256u * (unsigned)T + (unsigned)(r * RW);
}

__device__ __forceinline__ void decode_row(
    const float* cls, const float* codes, const float* props, int gid,
    float4& box, float& score)
{
    float2 lg = reinterpret_cast<const float2*>(cls)[gid];
    score = 1.0f / (1.0f + expf(lg.x - lg.y));
    float4 pb = reinterpret_cast<const float4*>(props)[gid];
    float4 c  = reinterpret_cast<const float4*>(codes)[gid * 2 + 1];
    float w  = pb.z - pb.x + 1.0f;
    float h  = pb.w - pb.y + 1.0f;
    float cx = pb.x + 0.5f * w;
    float cy = pb.y + 0.5f * h;
    float dx = c.x / 10.0f;
    float dy = c.y / 10.0f;
    float dw = fminf(c.z / 5.0f, XCLIP);
    float dh = fminf(c.w / 5.0f, XCLIP);
    float pcx = dx * w + cx;
    float pcy = dy * h + cy;
    float pw  = expf(dw) * w;
    float ph  = expf(dh) * h;
    float x1 = pcx - 0.5f * pw;
    float y1 = pcy - 0.5f * ph;
    float x2 = (pcx + 0.5f * pw) - 1.0f;
    float y2 = (pcy + 0.5f * ph) - 1.0f;
    box.x = fminf(fmaxf(x1, 0.0f), IMW - 1.0f);
    box.y = fminf(fmaxf(y1, 0.0f), IMH - 1.0f);
    box.z = fminf(fmaxf(x2, 0.0f), IMW - 1.0f);
    box.w = fminf(fmaxf(y2, 0.0f), IMH - 1.0f);
}

// ---------------------------------------------------------------------------
// K1: fused key-gen + stable rank-by-counting + decode + scatter sorted rows
// ---------------------------------------------------------------------------
__global__ __launch_bounds__(512) void rank_kernel(
    const float* __restrict__ cls, const float* __restrict__ codes,
    const float* __restrict__ props, float* __restrict__ out)
{
#pragma clang fp contract(off)
    __shared__ unsigned int sk[P_N];
    __shared__ unsigned short pc[512];
    const int img = blockIdx.x >> 5;   // 32 blocks per image
    const int blk = blockIdx.x & 31;   // 64 rows per block
    const int tid = threadIdx.x;

    for (int p = tid; p < P_N; p += 512) {
        float2 lg = reinterpret_cast<const float2*>(cls)[img * P_N + p];
        float score = 1.0f / (1.0f + expf(lg.x - lg.y));
        float keyf = (score > SCORE_T) ? -score : __int_as_float(0x7f800000);
        sk[p] = fkey(keyf);
    }
    __syncthreads();

    const int il = tid >> 3, sub = tid & 7;      // 8 threads per row
    const int i  = blk * 64 + il;
    const unsigned int ki = sk[i];
    int cnt = 0;
    for (int t = 0; t < 256; ++t) {
        int j = sub + 8 * ((t + il) & 255);
        unsigned int kj = sk[j];
        cnt += (kj < ki) || (kj == ki && j < i);
    }
    pc[tid] = (unsigned short)cnt;
    __syncthreads();

    if (tid < 64) {
        const int i2 = blk * 64 + tid;
        int r = 0;
#pragma unroll
        for (int s = 0; s < 8; ++s) r += pc[tid * 8 + s];
        float4 b; float sc;
        decode_row(cls, codes, props, img * P_N + i2, b, sc);
        float* o = out + ((size_t)img * P_N + r) * 5;
        o[0] = b.x; o[1] = b.y; o[2] = b.z; o[3] = b.w; o[4] = sc;
    }
}

// ---------------------------------------------------------------------------
// K2: triangular mask, tile-transposed, ONE i-block per wave, NO LDS.
//   (validated round 12, absmax 0). readlane broadcast of i-boxes; exact
//   double-form predicate (validated rounds 7-9,12).
// ---------------------------------------------------------------------------
#define TM_WPB 4     // waves per block
#define TM_TPI 528   // tiles per image = 32*33/2
__global__ __launch_bounds__(64 * TM_WPB) void tmask_kernel(
    const float* __restrict__ out, unsigned int* __restrict__ tmask)
{
#pragma clang fp contract(off)
    const int tid  = threadIdx.x;
    const int wv   = tid >> 6;
    const int lane = tid & 63;

    const int W   = blockIdx.x * TM_WPB + wv;   // global wave id
    const int img = W / TM_TPI;
    int r = W - img * TM_TPI;
    int g = 0, acc = 0;
    while (acc + g + 1 <= r) { acc += g + 1; ++g; }
    const int c = r - acc;                      // 0 <= c <= g

    // lane's i-row (block c) in registers
    const float* oi = out + ((size_t)img * P_N + c * 64 + lane) * 5;
    const float ix1 = oi[0], iy1 = oi[1], ix2 = oi[2], iy2 = oi[3];
    const float iar = (ix2 - ix1) * (iy2 - iy1);

    // lane's j-row (block g)
    const float* oj = out + ((size_t)img * P_N + g * 64 + lane) * 5;
    const float jx1 = oj[0], jy1 = oj[1], jx2 = oj[2], jy2 = oj[3];
    const float aj  = (jx2 - jx1) * (jy2 - jy1);

    const int tlim = (c < g) ? 64 : lane;   // diagonal tile: need i < j
    const double C = 0x1.000001p-1;         // 0.5*(1+2^-24), exact in f64
    unsigned int w0 = 0, w1 = 0;

#pragma unroll
    for (int t = 0; t < 64; ++t) {
        float bx1 = __int_as_float(__builtin_amdgcn_readlane(__float_as_int(ix1), t));
        float by1 = __int_as_float(__builtin_amdgcn_readlane(__float_as_int(iy1), t));
        float bx2 = __int_as_float(__builtin_amdgcn_readlane(__float_as_int(ix2), t));
        float by2 = __int_as_float(__builtin_amdgcn_readlane(__float_as_int(iy2), t));
        float ai  = __int_as_float(__builtin_amdgcn_readlane(__float_as_int(iar), t));
        float ltx = fmaxf(bx1, jx1);
        float lty = fmaxf(by1, jy1);
        float rbx = fminf(bx2, jx2);
        float rby = fminf(by2, jy2);
        float wx = fmaxf(rbx - ltx, 0.0f);
        float wy = fmaxf(rby - lty, 0.0f);
        float inter = wx * wy;
        float denom = ((ai + aj) - inter) + 1e-9f;
        bool sup = ((double)inter > (double)denom * C);
        if (!(denom > 0.0f))
            sup = (inter > 0.0f) && (__float_as_uint(denom) == 0u);
        sup = sup && (t < tlim);
        if (t < 32) w0 |= (unsigned int)sup << t;
        else        w1 |= (unsigned int)sup << (t - 32);
    }

    unsigned int* dst = tmask + (size_t)img * IMG_TM_U32
                      + row_base(g * 64 + lane) + 2 * c;
    *reinterpret_cast<uint2*>(dst) = make_uint2(w0, w1);
}

// ---------------------------------------------------------------------------
// K3: EXACT 32-level forward block-sweep (replaces global Jacobi).
//   Triangular system: row j depends only on i<j, so a forward sweep over
//   64-row blocks is exact. Level g: the wave owning block g resolves its
//   diagonal via a wave-local ballot fixpoint (no barrier; converges by
//   prefix-stabilization in <= chain length), publishes kw[2g,2g+1], ONE
//   __syncthreads, then every thread ORs (mask_words & kw_words) into its
//   private sup. All word indices compile-time (template recursion over g).
//   kw words written once, read only after their level's barrier.
// ---------------------------------------------------------------------------
template<int G>
struct RowMask {
    static constexpr int Q  = G >> 1;
    static constexpr int NV = Q + 1;                 // uint4 count = RW/4
    static constexpr int NW = 2 * (G + 1);           // valid words
    static constexpr int RW = 4 * NV;
    static constexpr int TT = (G & 1) ? (Q + 1) * (Q + 1) : Q * (Q + 1);
    static constexpr int S  = 256 * TT;              // block start (words)
    uint4 m[NV];
    __device__ __forceinline__ void load(const unsigned int* tmi, int lane) {
        const uint4* p = reinterpret_cast<const uint4*>(tmi + S + lane * RW);
#pragma unroll
        for (int v = 0; v < NV; ++v) m[v] = p[v];
        if constexpr (NW < RW) {   // even G: padding words never written
            m[NV - 1].z = 0u; m[NV - 1].w = 0u;
        }
    }
};

// compile-time word extractor: word W of a RowMask<G> (0 if beyond valid)
template<int W, int G>
__device__ __forceinline__ unsigned int getw(const RowMask<G>& M) {
    if constexpr (W >= RowMask<G>::NW) {
        return 0u;
    } else {
        constexpr int v = W >> 2;
        constexpr int c = W & 3;
        if constexpr (c == 0) return M.m[v].x;
        else if constexpr (c == 1) return M.m[v].y;
        else if constexpr (c == 2) return M.m[v].z;
        else return M.m[v].w;
    }
}

template<int G1, int G2>
struct SweepState {
    RowMask<G1> M1;
    RowMask<G2> M2;
    bool v1, v2;
    bool sup1, sup2;
    bool k1, k2;
    int lane;
    unsigned int* kw;
};

template<int g, int G1, int G2>
__device__ __forceinline__ void sweep_level(SweepState<G1, G2>& S) {
    if constexpr (g < 32) {
        if constexpr (G1 == g || G2 == g) {
            constexpr bool first = (G1 == g);
            bool v, sup;
            unsigned long long diag;
            if constexpr (first) {
                v = S.v1; sup = S.sup1;
                diag = (((unsigned long long)getw<2 * g + 1>(S.M1)) << 32)
                     | getw<2 * g>(S.M1);
            } else {
                v = S.v2; sup = S.sup2;
                diag = (((unsigned long long)getw<2 * g + 1>(S.M2)) << 32)
                     | getw<2 * g>(S.M2);
            }
            // wave-local ballot fixpoint on the 64-row diagonal.
            // Prefix-stabilization: row r exact after <= r+1 iters => terminates.
            bool k = v && !sup;
            for (;;) {
                unsigned long long kb = __ballot(k);
                bool kn = v && !sup && ((kb & diag) == 0ull);
                if (__ballot(kn != k) == 0ull) break;
                k = kn;
            }
            unsigned long long kb = __ballot(k);
            if (S.lane == 0) {
                S.kw[2 * g]     = (unsigned int)kb;
                S.kw[2 * g + 1] = (unsigned int)(kb >> 32);
            }
            if constexpr (first) S.k1 = k; else S.k2 = k;
        }
        __syncthreads();   // kw[2g,2g+1] visible to all
        if constexpr (G1 > g) {
            unsigned int a = getw<2 * g>(S.M1) & S.kw[2 * g];
            unsigned int b = getw<2 * g + 1>(S.M1) & S.kw[2 * g + 1];
            S.sup1 = S.sup1 || ((a | b) != 0u);
        }
        if constexpr (G2 > g) {
            unsigned int a = getw<2 * g>(S.M2) & S.kw[2 * g];
            unsigned int b = getw<2 * g + 1>(S.M2) & S.kw[2 * g + 1];
            S.sup2 = S.sup2 || ((a | b) != 0u);
        }
        sweep_level<g + 1, G1, G2>(S);
    }
}

template<int G1, int G2>
__device__ __forceinline__ void sweep_body(
    float* __restrict__ out, const unsigned int* __restrict__ tmi,
    int img, int lane, unsigned int* kw)
{
    SweepState<G1, G2> S;
    S.M1.load(tmi, lane);
    S.M2.load(tmi, lane);
    const int j1 = G1 * 64 + lane, j2 = G2 * 64 + lane;
    S.v1 = out[((size_t)img * P_N + j1) * 5 + 4] > SCORE_T;
    S.v2 = out[((size_t)img * P_N + j2) * 5 + 4] > SCORE_T;
    S.sup1 = false; S.sup2 = false;
    S.k1 = false;   S.k2 = false;
    S.lane = lane;  S.kw = kw;

    sweep_level<0, G1, G2>(S);

    if (!S.k1) { float* o = out + ((size_t)img * P_N + j1) * 5;
        o[0] = 0.0f; o[1] = 0.0f; o[2] = 0.0f; o[3] = 0.0f; o[4] = 0.0f; }
    if (!S.k2) { float* o = out + ((size_t)img * P_N + j2) * 5;
        o[0] = 0.0f; o[1] = 0.0f; o[2] = 0.0f; o[3] = 0.0f; o[4] = 0.0f; }
}

__global__ __launch_bounds__(1024) void sweep_kernel(
    float* __restrict__ out, const unsigned int* __restrict__ tmask)
{
    __shared__ __align__(16) unsigned int kw[64];
    const int img = blockIdx.x, tid = threadIdx.x;
    const int wv = tid >> 6, lane = tid & 63;
    const unsigned int* tmi = tmask + (size_t)img * IMG_TM_U32;
    switch (wv) {
        case  0: sweep_body< 0, 31>(out, tmi, img, lane, kw); break;
        case  1: sweep_body< 1, 30>(out, tmi, img, lane, kw); break;
        case  2: sweep_body< 2, 29>(out, tmi, img, lane, kw); break;
        case  3: sweep_body< 3, 28>(out, tmi, img, lane, kw); break;
        case  4: sweep_body< 4, 27>(out, tmi, img, lane, kw); break;
        case  5: sweep_body< 5, 26>(out, tmi, img, lane, kw); break;
        case  6: sweep_body< 6, 25>(out, tmi, img, lane, kw); break;
        case  7: sweep_body< 7, 24>(out, tmi, img, lane, kw); break;
        case  8: sweep_body< 8, 23>(out, tmi, img, lane, kw); break;
        case  9: sweep_body< 9, 22>(out, tmi, img, lane, kw); break;
        case 10: sweep_body<10, 21>(out, tmi, img, lane, kw); break;
        case 11: sweep_body<11, 20>(out, tmi, img, lane, kw); break;
        case 12: sweep_body<12, 19>(out, tmi, img, lane, kw); break;
        case 13: sweep_body<13, 18>(out, tmi, img, lane, kw); break;
        case 14: sweep_body<14, 17>(out, tmi, img, lane, kw); break;
        case 15: sweep_body<15, 16>(out, tmi, img, lane, kw); break;
    }
}

// ---------------------------------------------------------------------------
// ws-too-small fallback (validated rounds 1-4): bitonic sort + serial cascade
// ---------------------------------------------------------------------------
__global__ __launch_bounds__(1024) void prep_sort_kernel(
    const float* __restrict__ cls, const float* __restrict__ codes,
    const float* __restrict__ props, float* __restrict__ out)
{
#pragma clang fp contract(off)
    __shared__ float4 sbox[P_N];
    __shared__ float  ssc[P_N];
    __shared__ unsigned long long skey[P_N];
    const int img = blockIdx.x;
    const int tid = threadIdx.x;

    for (int p = tid; p < P_N; p += 1024) {
        float4 b; float sc;
        decode_row(cls, codes, props, img * P_N + p, b, sc);
        sbox[p] = b;
        ssc[p]  = sc;
        float key = (sc > SCORE_T) ? -sc : __int_as_float(0x7f800000);
        skey[p] = (((unsigned long long)fkey(key)) << 32) | (unsigned int)p;
    }
    __syncthreads();
    for (int k = 2; k <= P_N; k <<= 1) {
        for (int j = k >> 1; j > 0; j >>= 1) {
            for (int t = tid; t < P_N; t += 1024) {
                int ixj = t ^ j;
                if (ixj > t) {
                    unsigned long long a = skey[t], b = skey[ixj];
                    bool up = ((t & k) == 0);
                    if ((a > b) == up) { skey[t] = b; skey[ixj] = a; }
                }
            }
            __syncthreads();
        }
    }
    for (int e = tid; e < P_N; e += 1024) {
        unsigned long long kv = skey[e];
        int idx = (int)(kv & 0xFFFFFFFFull);
        float4 b4 = sbox[idx];
        float  s  = ssc[idx];
        float* o = out + ((size_t)img * P_N + e) * 5;
        o[0] = b4.x; o[1] = b4.y; o[2] = b4.z; o[3] = b4.w; o[4] = s;
    }
}

__global__ __launch_bounds__(64) void nms_fallback(float* __restrict__ out)
{
#pragma clang fp contract(off)
    __shared__ float4 sb[P_N];
    const int img  = blockIdx.x;
    const int lane = threadIdx.x;
    unsigned int keep = 0;
    for (int b = 0; b < 32; ++b) {
        int p = lane * 32 + b;
        const float* o = out + ((size_t)img * P_N + p) * 5;
        sb[p] = make_float4(o[0], o[1], o[2], o[3]);
        if (o[4] > SCORE_T) keep |= (1u << b);
    }
    __syncthreads();
    for (int i = 0; i < P_N; ++i) {
        unsigned int kw =
            (unsigned int)__builtin_amdgcn_readlane((int)keep, i >> 5);
        if ((kw >> (i & 31)) & 1u) {
            float4 bi = sb[i];
            float area_i = (bi.z - bi.x) * (bi.w - bi.y);
            unsigned int m = 0;
            for (int b = 0; b < 32; ++b) {
                int j = lane * 32 + b;
                if (j > i) {
                    float4 bj = sb[j];
                    float area_j = (bj.z - bj.x) * (bj.w - bj.y);
                    float ltx = fmaxf(bi.x, bj.x);
                    float lty = fmaxf(bi.y, bj.y);
                    float rbx = fminf(bi.z, bj.z);
                    float rby = fminf(bi.w, bj.w);
                    float wx = fmaxf(rbx - ltx, 0.0f);
                    float wy = fmaxf(rby - lty, 0.0f);
                    float inter = wx * wy;
                    float denom = ((area_i + area_j) - inter) + 1e-9f;
                    if ((inter / denom) > 0.5f) m |= (1u << b);
                }
            }
            keep &= ~m;
        }
    }
    for (int b = 0; b < 32; ++b) {
        if (!((keep >> b) & 1u)) {
            int p = lane * 32 + b;
            float* o = out + ((size_t)img * P_N + p) * 5;
            o[0] = 0.0f; o[1] = 0.0f; o[2] = 0.0f; o[3] = 0.0f; o[4] = 0.0f;
        }
    }
}

// ---------------------------------------------------------------------------
extern "C" void kernel_launch(void* const* d_in, const int* in_sizes, int n_in,
                              void* d_out, int out_size, void* d_ws, size_t ws_size,
                              hipStream_t stream) {
    const float* cls   = (const float*)d_in[0];
    const float* codes = (const float*)d_in[1];
    const float* props = (const float*)d_in[2];
    float* out = (float*)d_out;

    const size_t tmask_bytes = (size_t)B_IMG * IMG_TM_U32 * 4;   // 4.46 MB

    if (ws_size >= tmask_bytes) {
        unsigned int* tmask = (unsigned int*)d_ws;
        rank_kernel<<<B_IMG * 32, 512, 0, stream>>>(cls, codes, props, out);
        tmask_kernel<<<(B_IMG * TM_TPI) / TM_WPB, 64 * TM_WPB, 0, stream>>>(out, tmask);
        sweep_kernel<<<B_IMG, 1024, 0, stream>>>(out, tmask);
    } else {
        prep_sort_kernel<<<B_IMG, 1024, 0, stream>>>(cls, codes, props, out);
        nms_fallback<<<B_IMG, 64, 0, stream>>>(out);
    }
}

// Round 14
// 75.841 us; speedup vs baseline: 1.0879x; 1.0306x over previous
//
#include <hip/hip_runtime.h>
#include <math.h>

#define B_IMG 16
#define P_N   2048
#define IMG_TM_U32 69632   // per-image padded triangular mask u32 words

constexpr float SCORE_T = 0.05f;
constexpr float XCLIP   = 4.135166556742356f; // log(1000/16)
constexpr float IMW     = 1333.0f;
constexpr float IMH     = 800.0f;

// monotone float->uint mapping (ascending float order, incl +inf)
__device__ __forceinline__ unsigned int fkey(float f) {
    unsigned int u = __float_as_uint(f);
    return (u & 0x80000000u) ? ~u : (u | 0x80000000u);
}

// Padded triangular layout: block b rows have RW(b)=4*((b>>1)+1) u32 words,
// 16B-aligned. Block start S(b) = 256*T(b), T(b) = (b&1)?(q+1)^2 : q(q+1).
__device__ __forceinline__ unsigned int row_base(int j) {
    int b = j >> 6, r = j & 63;
    int q = b >> 1;
    int T = (b & 1) ? (q + 1) * (q + 1) : q * (q + 1);
    int RW = 4 * (q + 1);
    return 256u * (unsigned)T + (unsigned)(r * RW);
}

__device__ __forceinline__ void decode_row(
    const float* cls, const float* codes, const float* props, int gid,
    float4& box, float& score)
{
    float2 lg = reinterpret_cast<const float2*>(cls)[gid];
    score = 1.0f / (1.0f + expf(lg.x - lg.y));
    float4 pb = reinterpret_cast<const float4*>(props)[gid];
    float4 c  = reinterpret_cast<const float4*>(codes)[gid * 2 + 1];
    float w  = pb.z - pb.x + 1.0f;
    float h  = pb.w - pb.y + 1.0f;
    float cx = pb.x + 0.5f * w;
    float cy = pb.y + 0.5f * h;
    float dx = c.x / 10.0f;
    float dy = c.y / 10.0f;
    float dw = fminf(c.z / 5.0f, XCLIP);
    float dh = fminf(c.w / 5.0f, XCLIP);
    float pcx = dx * w + cx;
    float pcy = dy * h + cy;
    float pw  = expf(dw) * w;
    float ph  = expf(dh) * h;
    float x1 = pcx - 0.5f * pw;
    float y1 = pcy - 0.5f * ph;
    float x2 = (pcx + 0.5f * pw) - 1.0f;
    float y2 = (pcy + 0.5f * ph) - 1.0f;
    box.x = fminf(fmaxf(x1, 0.0f), IMW - 1.0f);
    box.y = fminf(fmaxf(y1, 0.0f), IMH - 1.0f);
    box.z = fminf(fmaxf(x2, 0.0f), IMW - 1.0f);
    box.w = fminf(fmaxf(y2, 0.0f), IMH - 1.0f);
}

// ---------------------------------------------------------------------------
// K1: fused key-gen + stable rank-by-counting + decode + scatter sorted rows
// ---------------------------------------------------------------------------
__global__ __launch_bounds__(512) void rank_kernel(
    const float* __restrict__ cls, const float* __restrict__ codes,
    const float* __restrict__ props, float* __restrict__ out)
{
#pragma clang fp contract(off)
    __shared__ unsigned int sk[P_N];
    __shared__ unsigned short pc[512];
    const int img = blockIdx.x >> 5;   // 32 blocks per image
    const int blk = blockIdx.x & 31;   // 64 rows per block
    const int tid = threadIdx.x;

    for (int p = tid; p < P_N; p += 512) {
        float2 lg = reinterpret_cast<const float2*>(cls)[img * P_N + p];
        float score = 1.0f / (1.0f + expf(lg.x - lg.y));
        float keyf = (score > SCORE_T) ? -score : __int_as_float(0x7f800000);
        sk[p] = fkey(keyf);
    }
    __syncthreads();

    const int il = tid >> 3, sub = tid & 7;      // 8 threads per row
    const int i  = blk * 64 + il;
    const unsigned int ki = sk[i];
    int cnt = 0;
    for (int t = 0; t < 256; ++t) {
        int j = sub + 8 * ((t + il) & 255);
        unsigned int kj = sk[j];
        cnt += (kj < ki) || (kj == ki && j < i);
    }
    pc[tid] = (unsigned short)cnt;
    __syncthreads();

    if (tid < 64) {
        const int i2 = blk * 64 + tid;
        int r = 0;
#pragma unroll
        for (int s = 0; s < 8; ++s) r += pc[tid * 8 + s];
        float4 b; float sc;
        decode_row(cls, codes, props, img * P_N + i2, b, sc);
        float* o = out + ((size_t)img * P_N + r) * 5;
        o[0] = b.x; o[1] = b.y; o[2] = b.z; o[3] = b.w; o[4] = sc;
    }
}

// ---------------------------------------------------------------------------
// K2: triangular mask, tile-transposed, ONE i-block per wave, NO LDS.
//   readlane broadcast of i-boxes (validated round 12/13).
//   EXACT PURE-F32 predicate (replaces the f64 form, provably equivalent):
//     For denom>0 (normal, >=1e-9): RN(inter/denom)>0.5
//       <=> real inter > denom*(0.5+2^-25) = h + h*2^-24,  h = 0.5f*denom
//           (h exact: exponent shift). Since 0 < h*2^-24 < ulp(h) for all
//           normal h (mantissa<2), the threshold lies strictly BETWEEN the
//           consecutive f32s h and h+ulp(h); no f32 `inter` falls in that
//           gap, so the condition collapses to plain  inter > h  in f32.
//           Equality inter == h+h*2^-24 is unrepresentable.
//     Corroboration: R10 (fmaf form of this) and R11 (double form) failed
//     with IDENTICAL absmax under the buggy 1-barrier fixpoint -> the two
//     predicates agree on this data; R10's failure was the fixpoint.
//     denom<=+-0: quotient is <=0 or NaN except denom==+0 && inter>0 (+inf)
//     -- handled by the explicit branch (unchanged, validated).
// ---------------------------------------------------------------------------
#define TM_WPB 4     // waves per block
#define TM_TPI 528   // tiles per image = 32*33/2
__global__ __launch_bounds__(64 * TM_WPB) void tmask_kernel(
    const float* __restrict__ out, unsigned int* __restrict__ tmask)
{
#pragma clang fp contract(off)
    const int tid  = threadIdx.x;
    const int wv   = tid >> 6;
    const int lane = tid & 63;

    const int W   = blockIdx.x * TM_WPB + wv;   // global wave id
    const int img = W / TM_TPI;
    int r = W - img * TM_TPI;
    int g = 0, acc = 0;
    while (acc + g + 1 <= r) { acc += g + 1; ++g; }
    const int c = r - acc;                      // 0 <= c <= g

    // lane's i-row (block c) in registers
    const float* oi = out + ((size_t)img * P_N + c * 64 + lane) * 5;
    const float ix1 = oi[0], iy1 = oi[1], ix2 = oi[2], iy2 = oi[3];
    const float iar = (ix2 - ix1) * (iy2 - iy1);

    // lane's j-row (block g)
    const float* oj = out + ((size_t)img * P_N + g * 64 + lane) * 5;
    const float jx1 = oj[0], jy1 = oj[1], jx2 = oj[2], jy2 = oj[3];
    const float aj  = (jx2 - jx1) * (jy2 - jy1);

    const int tlim = (c < g) ? 64 : lane;   // diagonal tile: need i < j
    unsigned int w0 = 0, w1 = 0;

#pragma unroll
    for (int t = 0; t < 64; ++t) {
        float bx1 = __int_as_float(__builtin_amdgcn_readlane(__float_as_int(ix1), t));
        float by1 = __int_as_float(__builtin_amdgcn_readlane(__float_as_int(iy1), t));
        float bx2 = __int_as_float(__builtin_amdgcn_readlane(__float_as_int(ix2), t));
        float by2 = __int_as_float(__builtin_amdgcn_readlane(__float_as_int(iy2), t));
        float ai  = __int_as_float(__builtin_amdgcn_readlane(__float_as_int(iar), t));
        float ltx = fmaxf(bx1, jx1);
        float lty = fmaxf(by1, jy1);
        float rbx = fminf(bx2, jx2);
        float rby = fminf(by2, jy2);
        float wx = fmaxf(rbx - ltx, 0.0f);
        float wy = fmaxf(rby - lty, 0.0f);
        float inter = wx * wy;
        float denom = ((ai + aj) - inter) + 1e-9f;
        bool sup = inter > 0.5f * denom;        // exact (see header proof)
        if (!(denom > 0.0f))
            sup = (inter > 0.0f) && (__float_as_uint(denom) == 0u);
        sup = sup && (t < tlim);
        if (t < 32) w0 |= (unsigned int)sup << t;
        else        w1 |= (unsigned int)sup << (t - 32);
    }

    unsigned int* dst = tmask + (size_t)img * IMG_TM_U32
                      + row_base(g * 64 + lane) + 2 * c;
    *reinterpret_cast<uint2*>(dst) = make_uint2(w0, w1);
}

// ---------------------------------------------------------------------------
// K3: EXACT 32-level forward block-sweep (validated round 13).
// ---------------------------------------------------------------------------
template<int G>
struct RowMask {
    static constexpr int Q  = G >> 1;
    static constexpr int NV = Q + 1;                 // uint4 count = RW/4
    static constexpr int NW = 2 * (G + 1);           // valid words
    static constexpr int RW = 4 * NV;
    static constexpr int TT = (G & 1) ? (Q + 1) * (Q + 1) : Q * (Q + 1);
    static constexpr int S  = 256 * TT;              // block start (words)
    uint4 m[NV];
    __device__ __forceinline__ void load(const unsigned int* tmi, int lane) {
        const uint4* p = reinterpret_cast<const uint4*>(tmi + S + lane * RW);
#pragma unroll
        for (int v = 0; v < NV; ++v) m[v] = p[v];
        if constexpr (NW < RW) {   // even G: padding words never written
            m[NV - 1].z = 0u; m[NV - 1].w = 0u;
        }
    }
};

// compile-time word extractor: word W of a RowMask<G> (0 if beyond valid)
template<int W, int G>
__device__ __forceinline__ unsigned int getw(const RowMask<G>& M) {
    if constexpr (W >= RowMask<G>::NW) {
        return 0u;
    } else {
        constexpr int v = W >> 2;
        constexpr int c = W & 3;
        if constexpr (c == 0) return M.m[v].x;
        else if constexpr (c == 1) return M.m[v].y;
        else if constexpr (c == 2) return M.m[v].z;
        else return M.m[v].w;
    }
}

template<int G1, int G2>
struct SweepState {
    RowMask<G1> M1;
    RowMask<G2> M2;
    bool v1, v2;
    bool sup1, sup2;
    bool k1, k2;
    int lane;
    unsigned int* kw;
};

template<int g, int G1, int G2>
__device__ __forceinline__ void sweep_level(SweepState<G1, G2>& S) {
    if constexpr (g < 32) {
        if constexpr (G1 == g || G2 == g) {
            constexpr bool first = (G1 == g);
            bool v, sup;
            unsigned long long diag;
            if constexpr (first) {
                v = S.v1; sup = S.sup1;
                diag = (((unsigned long long)getw<2 * g + 1>(S.M1)) << 32)
                     | getw<2 * g>(S.M1);
            } else {
                v = S.v2; sup = S.sup2;
                diag = (((unsigned long long)getw<2 * g + 1>(S.M2)) << 32)
                     | getw<2 * g>(S.M2);
            }
            // wave-local ballot fixpoint on the 64-row diagonal.
            bool k = v && !sup;
            for (;;) {
                unsigned long long kb = __ballot(k);
                bool kn = v && !sup && ((kb & diag) == 0ull);
                if (__ballot(kn != k) == 0ull) break;
                k = kn;
            }
            unsigned long long kb = __ballot(k);
            if (S.lane == 0) {
                S.kw[2 * g]     = (unsigned int)kb;
                S.kw[2 * g + 1] = (unsigned int)(kb >> 32);
            }
            if constexpr (first) S.k1 = k; else S.k2 = k;
        }
        __syncthreads();   // kw[2g,2g+1] visible to all
        if constexpr (G1 > g) {
            unsigned int a = getw<2 * g>(S.M1) & S.kw[2 * g];
            unsigned int b = getw<2 * g + 1>(S.M1) & S.kw[2 * g + 1];
            S.sup1 = S.sup1 || ((a | b) != 0u);
        }
        if constexpr (G2 > g) {
            unsigned int a = getw<2 * g>(S.M2) & S.kw[2 * g];
            unsigned int b = getw<2 * g + 1>(S.M2) & S.kw[2 * g + 1];
            S.sup2 = S.sup2 || ((a | b) != 0u);
        }
        sweep_level<g + 1, G1, G2>(S);
    }
}

template<int G1, int G2>
__device__ __forceinline__ void sweep_body(
    float* __restrict__ out, const unsigned int* __restrict__ tmi,
    int img, int lane, unsigned int* kw)
{
    SweepState<G1, G2> S;
    S.M1.load(tmi, lane);
    S.M2.load(tmi, lane);
    const int j1 = G1 * 64 + lane, j2 = G2 * 64 + lane;
    S.v1 = out[((size_t)img * P_N + j1) * 5 + 4] > SCORE_T;
    S.v2 = out[((size_t)img * P_N + j2) * 5 + 4] > SCORE_T;
    S.sup1 = false; S.sup2 = false;
    S.k1 = false;   S.k2 = false;
    S.lane = lane;  S.kw = kw;

    sweep_level<0, G1, G2>(S);

    if (!S.k1) { float* o = out + ((size_t)img * P_N + j1) * 5;
        o[0] = 0.0f; o[1] = 0.0f; o[2] = 0.0f; o[3] = 0.0f; o[4] = 0.0f; }
    if (!S.k2) { float* o = out + ((size_t)img * P_N + j2) * 5;
        o[0] = 0.0f; o[1] = 0.0f; o[2] = 0.0f; o[3] = 0.0f; o[4] = 0.0f; }
}

__global__ __launch_bounds__(1024) void sweep_kernel(
    float* __restrict__ out, const unsigned int* __restrict__ tmask)
{
    __shared__ __align__(16) unsigned int kw[64];
    const int img = blockIdx.x, tid = threadIdx.x;
    const int wv = tid >> 6, lane = tid & 63;
    const unsigned int* tmi = tmask + (size_t)img * IMG_TM_U32;
    switch (wv) {
        case  0: sweep_body< 0, 31>(out, tmi, img, lane, kw); break;
        case  1: sweep_body< 1, 30>(out, tmi, img, lane, kw); break;
        case  2: sweep_body< 2, 29>(out, tmi, img, lane, kw); break;
        case  3: sweep_body< 3, 28>(out, tmi, img, lane, kw); break;
        case  4: sweep_body< 4, 27>(out, tmi, img, lane, kw); break;
        case  5: sweep_body< 5, 26>(out, tmi, img, lane, kw); break;
        case  6: sweep_body< 6, 25>(out, tmi, img, lane, kw); break;
        case  7: sweep_body< 7, 24>(out, tmi, img, lane, kw); break;
        case  8: sweep_body< 8, 23>(out, tmi, img, lane, kw); break;
        case  9: sweep_body< 9, 22>(out, tmi, img, lane, kw); break;
        case 10: sweep_body<10, 21>(out, tmi, img, lane, kw); break;
        case 11: sweep_body<11, 20>(out, tmi, img, lane, kw); break;
        case 12: sweep_body<12, 19>(out, tmi, img, lane, kw); break;
        case 13: sweep_body<13, 18>(out, tmi, img, lane, kw); break;
        case 14: sweep_body<14, 17>(out, tmi, img, lane, kw); break;
        case 15: sweep_body<15, 16>(out, tmi, img, lane, kw); break;
    }
}

// ---------------------------------------------------------------------------
// ws-too-small fallback (validated rounds 1-4): bitonic sort + serial cascade
// ---------------------------------------------------------------------------
__global__ __launch_bounds__(1024) void prep_sort_kernel(
    const float* __restrict__ cls, const float* __restrict__ codes,
    const float* __restrict__ props, float* __restrict__ out)
{
#pragma clang fp contract(off)
    __shared__ float4 sbox[P_N];
    __shared__ float  ssc[P_N];
    __shared__ unsigned long long skey[P_N];
    const int img = blockIdx.x;
    const int tid = threadIdx.x;

    for (int p = tid; p < P_N; p += 1024) {
        float4 b; float sc;
        decode_row(cls, codes, props, img * P_N + p, b, sc);
        sbox[p] = b;
        ssc[p]  = sc;
        float key = (sc > SCORE_T) ? -sc : __int_as_float(0x7f800000);
        skey[p] = (((unsigned long long)fkey(key)) << 32) | (unsigned int)p;
    }
    __syncthreads();
    for (int k = 2; k <= P_N; k <<= 1) {
        for (int j = k >> 1; j > 0; j >>= 1) {
            for (int t = tid; t < P_N; t += 1024) {
                int ixj = t ^ j;
                if (ixj > t) {
                    unsigned long long a = skey[t], b = skey[ixj];
                    bool up = ((t & k) == 0);
                    if ((a > b) == up) { skey[t] = b; skey[ixj] = a; }
                }
            }
            __syncthreads();
        }
    }
    for (int e = tid; e < P_N; e += 1024) {
        unsigned long long kv = skey[e];
        int idx = (int)(kv & 0xFFFFFFFFull);
        float4 b4 = sbox[idx];
        float  s  = ssc[idx];
        float* o = out + ((size_t)img * P_N + e) * 5;
        o[0] = b4.x; o[1] = b4.y; o[2] = b4.z; o[3] = b4.w; o[4] = s;
    }
}

__global__ __launch_bounds__(64) void nms_fallback(float* __restrict__ out)
{
#pragma clang fp contract(off)
    __shared__ float4 sb[P_N];
    const int img  = blockIdx.x;
    const int lane = threadIdx.x;
    unsigned int keep = 0;
    for (int b = 0; b < 32; ++b) {
        int p = lane * 32 + b;
        const float* o = out + ((size_t)img * P_N + p) * 5;
        sb[p] = make_float4(o[0], o[1], o[2], o[3]);
        if (o[4] > SCORE_T) keep |= (1u << b);
    }
    __syncthreads();
    for (int i = 0; i < P_N; ++i) {
        unsigned int kw =
            (unsigned int)__builtin_amdgcn_readlane((int)keep, i >> 5);
        if ((kw >> (i & 31)) & 1u) {
            float4 bi = sb[i];
            float area_i = (bi.z - bi.x) * (bi.w - bi.y);
            unsigned int m = 0;
            for (int b = 0; b < 32; ++b) {
                int j = lane * 32 + b;
                if (j > i) {
                    float4 bj = sb[j];
                    float area_j = (bj.z - bj.x) * (bj.w - bj.y);
                    float ltx = fmaxf(bi.x, bj.x);
                    float lty = fmaxf(bi.y, bj.y);
                    float rbx = fminf(bi.z, bj.z);
                    float rby = fminf(bi.w, bj.w);
                    float wx = fmaxf(rbx - ltx, 0.0f);
                    float wy = fmaxf(rby - lty, 0.0f);
                    float inter = wx * wy;
                    float denom = ((area_i + area_j) - inter) + 1e-9f;
                    if ((inter / denom) > 0.5f) m |= (1u << b);
                }
            }
            keep &= ~m;
        }
    }
    for (int b = 0; b < 32; ++b) {
        if (!((keep >> b) & 1u)) {
            int p = lane * 32 + b;
            float* o = out + ((size_t)img * P_N + p) * 5;
            o[0] = 0.0f; o[1] = 0.0f; o[2] = 0.0f; o[3] = 0.0f; o[4] = 0.0f;
        }
    }
}

// ---------------------------------------------------------------------------
extern "C" void kernel_launch(void* const* d_in, const int* in_sizes, int n_in,
                              void* d_out, int out_size, void* d_ws, size_t ws_size,
                              hipStream_t stream) {
    const float* cls   = (const float*)d_in[0];
    const float* codes = (const float*)d_in[1];
    const float* props = (const float*)d_in[2];
    float* out = (float*)d_out;

    const size_t tmask_bytes = (size_t)B_IMG * IMG_TM_U32 * 4;   // 4.46 MB

    if (ws_size >= tmask_bytes) {
        unsigned int* tmask = (unsigned int*)d_ws;
        rank_kernel<<<B_IMG * 32, 512, 0, stream>>>(cls, codes, props, out);
        tmask_kernel<<<(B_IMG * TM_TPI) / TM_WPB, 64 * TM_WPB, 0, stream>>>(out, tmask);
        sweep_kernel<<<B_IMG, 1024, 0, stream>>>(out, tmask);
    } else {
        prep_sort_kernel<<<B_IMG, 1024, 0, stream>>>(cls, codes, props, out);
        nms_fallback<<<B_IMG, 64, 0, stream>>>(out);
    }
}

// Round 15
// 75.715 us; speedup vs baseline: 1.0898x; 1.0017x over previous
//
#include <hip/hip_runtime.h>
#include <math.h>

#define B_IMG 16
#define P_N   2048
#define IMG_TM_U32 69632   // per-image padded triangular mask u32 words

constexpr float SCORE_T = 0.05f;
constexpr float XCLIP   = 4.135166556742356f; // log(1000/16)
constexpr float IMW     = 1333.0f;
constexpr float IMH     = 800.0f;

// monotone float->uint mapping (ascending float order, incl +inf)
__device__ __forceinline__ unsigned int fkey(float f) {
    unsigned int u = __float_as_uint(f);
    return (u & 0x80000000u) ? ~u : (u | 0x80000000u);
}

// Padded triangular layout: block b rows have RW(b)=4*((b>>1)+1) u32 words,
// 16B-aligned. Block start S(b) = 256*T(b), T(b) = (b&1)?(q+1)^2 : q(q+1).
__device__ __forceinline__ unsigned int row_base(int j) {
    int b = j >> 6, r = j & 63;
    int q = b >> 1;
    int T = (b & 1) ? (q + 1) * (q + 1) : q * (q + 1);
    int RW = 4 * (q + 1);
    return 256u * (unsigned)T + (unsigned)(r * RW);
}

__device__ __forceinline__ void decode_row(
    const float* cls, const float* codes, const float* props, int gid,
    float4& box, float& score)
{
    float2 lg = reinterpret_cast<const float2*>(cls)[gid];
    score = 1.0f / (1.0f + expf(lg.x - lg.y));
    float4 pb = reinterpret_cast<const float4*>(props)[gid];
    float4 c  = reinterpret_cast<const float4*>(codes)[gid * 2 + 1];
    float w  = pb.z - pb.x + 1.0f;
    float h  = pb.w - pb.y + 1.0f;
    float cx = pb.x + 0.5f * w;
    float cy = pb.y + 0.5f * h;
    float dx = c.x / 10.0f;
    float dy = c.y / 10.0f;
    float dw = fminf(c.z / 5.0f, XCLIP);
    float dh = fminf(c.w / 5.0f, XCLIP);
    float pcx = dx * w + cx;
    float pcy = dy * h + cy;
    float pw  = expf(dw) * w;
    float ph  = expf(dh) * h;
    float x1 = pcx - 0.5f * pw;
    float y1 = pcy - 0.5f * ph;
    float x2 = (pcx + 0.5f * pw) - 1.0f;
    float y2 = (pcy + 0.5f * ph) - 1.0f;
    box.x = fminf(fmaxf(x1, 0.0f), IMW - 1.0f);
    box.y = fminf(fmaxf(y1, 0.0f), IMH - 1.0f);
    box.z = fminf(fmaxf(x2, 0.0f), IMW - 1.0f);
    box.w = fminf(fmaxf(y2, 0.0f), IMH - 1.0f);
}

// ---------------------------------------------------------------------------
// K1: fused key-gen + stable rank-by-counting + decode + scatter sorted rows.
//   Additionally scatters boxes4/area/scores scratch (sorted order) so tmask
//   and sweep get coalesced, vectorized loads instead of stride-20 scalars.
// ---------------------------------------------------------------------------
__global__ __launch_bounds__(512) void rank_kernel(
    const float* __restrict__ cls, const float* __restrict__ codes,
    const float* __restrict__ props, float* __restrict__ out,
    float4* __restrict__ boxes4, float* __restrict__ area,
    float* __restrict__ scores)
{
#pragma clang fp contract(off)
    __shared__ unsigned int sk[P_N];
    __shared__ unsigned short pc[512];
    const int img = blockIdx.x >> 5;   // 32 blocks per image
    const int blk = blockIdx.x & 31;   // 64 rows per block
    const int tid = threadIdx.x;

    for (int p = tid; p < P_N; p += 512) {
        float2 lg = reinterpret_cast<const float2*>(cls)[img * P_N + p];
        float score = 1.0f / (1.0f + expf(lg.x - lg.y));
        float keyf = (score > SCORE_T) ? -score : __int_as_float(0x7f800000);
        sk[p] = fkey(keyf);
    }
    __syncthreads();

    const int il = tid >> 3, sub = tid & 7;      // 8 threads per row
    const int i  = blk * 64 + il;
    const unsigned int ki = sk[i];
    int cnt = 0;
    for (int t = 0; t < 256; ++t) {
        int j = sub + 8 * ((t + il) & 255);
        unsigned int kj = sk[j];
        cnt += (kj < ki) || (kj == ki && j < i);
    }
    pc[tid] = (unsigned short)cnt;
    __syncthreads();

    if (tid < 64) {
        const int i2 = blk * 64 + tid;
        int r = 0;
#pragma unroll
        for (int s = 0; s < 8; ++s) r += pc[tid * 8 + s];
        float4 b; float sc;
        decode_row(cls, codes, props, img * P_N + i2, b, sc);
        float* o = out + ((size_t)img * P_N + r) * 5;
        o[0] = b.x; o[1] = b.y; o[2] = b.z; o[3] = b.w; o[4] = sc;
        boxes4[img * P_N + r] = b;
        area[img * P_N + r]   = (b.z - b.x) * (b.w - b.y);
        scores[img * P_N + r] = sc;
    }
}

// ---------------------------------------------------------------------------
// K2: triangular mask, tile-transposed, ONE i-block per wave, NO LDS.
//   readlane broadcast of i-boxes (validated rounds 12-14). Split plain/diag
//   loops (removes runtime tlim test from 94% of tiles). Coalesced float4
//   box loads + precomputed areas from rank's scratch.
//   EXACT PURE-F32 predicate (validated round 14): for denom>0,
//   RN(inter/denom)>0.5 <=> inter > 0.5f*denom (threshold h+h*2^-24 lies
//   strictly between consecutive f32s h, h+ulp(h)); denom<=+-0 explicit.
// ---------------------------------------------------------------------------
#define TM_WPB 4     // waves per block
#define TM_TPI 528   // tiles per image = 32*33/2
__global__ __launch_bounds__(64 * TM_WPB) void tmask_kernel(
    const float4* __restrict__ boxes4, const float* __restrict__ area,
    unsigned int* __restrict__ tmask)
{
#pragma clang fp contract(off)
    const int tid  = threadIdx.x;
    const int wv   = tid >> 6;
    const int lane = tid & 63;

    const int W   = blockIdx.x * TM_WPB + wv;   // global wave id
    const int img = W / TM_TPI;
    int r = W - img * TM_TPI;
    int g = 0, acc = 0;
    while (acc + g + 1 <= r) { acc += g + 1; ++g; }
    const int c = r - acc;                      // 0 <= c <= g

    // lane's i-row (block c) in registers — coalesced float4 + area
    const float4 bi4 = boxes4[img * P_N + c * 64 + lane];
    const float ix1 = bi4.x, iy1 = bi4.y, ix2 = bi4.z, iy2 = bi4.w;
    const float iar = area[img * P_N + c * 64 + lane];

    // lane's j-row (block g)
    const float4 bj4 = boxes4[img * P_N + g * 64 + lane];
    const float jx1 = bj4.x, jy1 = bj4.y, jx2 = bj4.z, jy2 = bj4.w;
    const float aj  = area[img * P_N + g * 64 + lane];

    unsigned int w0 = 0, w1 = 0;

#define IOU_T(T, DIAG)                                                        \
    {                                                                         \
        float bx1 = __int_as_float(__builtin_amdgcn_readlane(__float_as_int(ix1), (T))); \
        float by1 = __int_as_float(__builtin_amdgcn_readlane(__float_as_int(iy1), (T))); \
        float bx2 = __int_as_float(__builtin_amdgcn_readlane(__float_as_int(ix2), (T))); \
        float by2 = __int_as_float(__builtin_amdgcn_readlane(__float_as_int(iy2), (T))); \
        float ai  = __int_as_float(__builtin_amdgcn_readlane(__float_as_int(iar), (T))); \
        float ltx = fmaxf(bx1, jx1);                                          \
        float lty = fmaxf(by1, jy1);                                          \
        float rbx = fminf(bx2, jx2);                                          \
        float rby = fminf(by2, jy2);                                          \
        float wx = fmaxf(rbx - ltx, 0.0f);                                    \
        float wy = fmaxf(rby - lty, 0.0f);                                    \
        float inter = wx * wy;                                                \
        float denom = ((ai + aj) - inter) + 1e-9f;                            \
        bool sup = inter > 0.5f * denom;                                      \
        if (!(denom > 0.0f))                                                  \
            sup = (inter > 0.0f) && (__float_as_uint(denom) == 0u);           \
        if (DIAG) sup = sup && ((T) < lane);                                  \
        if ((T) < 32) w0 |= (unsigned int)sup << (T);                         \
        else          w1 |= (unsigned int)sup << ((T) - 32);                  \
    }

    if (c < g) {        // plain tile: no index test at all
#pragma unroll
        for (int t = 0; t < 64; ++t) IOU_T(t, false)
    } else {            // diagonal tile: need i < j
#pragma unroll
        for (int t = 0; t < 64; ++t) IOU_T(t, true)
    }
#undef IOU_T

    unsigned int* dst = tmask + (size_t)img * IMG_TM_U32
                      + row_base(g * 64 + lane) + 2 * c;
    *reinterpret_cast<uint2*>(dst) = make_uint2(w0, w1);
}

// ---------------------------------------------------------------------------
// K3: EXACT 32-level forward block-sweep (validated rounds 13-14).
// ---------------------------------------------------------------------------
template<int G>
struct RowMask {
    static constexpr int Q  = G >> 1;
    static constexpr int NV = Q + 1;                 // uint4 count = RW/4
    static constexpr int NW = 2 * (G + 1);           // valid words
    static constexpr int RW = 4 * NV;
    static constexpr int TT = (G & 1) ? (Q + 1) * (Q + 1) : Q * (Q + 1);
    static constexpr int S  = 256 * TT;              // block start (words)
    uint4 m[NV];
    __device__ __forceinline__ void load(const unsigned int* tmi, int lane) {
        const uint4* p = reinterpret_cast<const uint4*>(tmi + S + lane * RW);
#pragma unroll
        for (int v = 0; v < NV; ++v) m[v] = p[v];
        if constexpr (NW < RW) {   // even G: padding words never written
            m[NV - 1].z = 0u; m[NV - 1].w = 0u;
        }
    }
};

// compile-time word extractor: word W of a RowMask<G> (0 if beyond valid)
template<int W, int G>
__device__ __forceinline__ unsigned int getw(const RowMask<G>& M) {
    if constexpr (W >= RowMask<G>::NW) {
        return 0u;
    } else {
        constexpr int v = W >> 2;
        constexpr int c = W & 3;
        if constexpr (c == 0) return M.m[v].x;
        else if constexpr (c == 1) return M.m[v].y;
        else if constexpr (c == 2) return M.m[v].z;
        else return M.m[v].w;
    }
}

template<int G1, int G2>
struct SweepState {
    RowMask<G1> M1;
    RowMask<G2> M2;
    bool v1, v2;
    bool sup1, sup2;
    bool k1, k2;
    int lane;
    unsigned int* kw;
};

template<int g, int G1, int G2>
__device__ __forceinline__ void sweep_level(SweepState<G1, G2>& S) {
    if constexpr (g < 32) {
        if constexpr (G1 == g || G2 == g) {
            constexpr bool first = (G1 == g);
            bool v, sup;
            unsigned long long diag;
            if constexpr (first) {
                v = S.v1; sup = S.sup1;
                diag = (((unsigned long long)getw<2 * g + 1>(S.M1)) << 32)
                     | getw<2 * g>(S.M1);
            } else {
                v = S.v2; sup = S.sup2;
                diag = (((unsigned long long)getw<2 * g + 1>(S.M2)) << 32)
                     | getw<2 * g>(S.M2);
            }
            // wave-local ballot fixpoint on the 64-row diagonal.
            bool k = v && !sup;
            for (;;) {
                unsigned long long kb = __ballot(k);
                bool kn = v && !sup && ((kb & diag) == 0ull);
                if (__ballot(kn != k) == 0ull) break;
                k = kn;
            }
            unsigned long long kb = __ballot(k);
            if (S.lane == 0) {
                S.kw[2 * g]     = (unsigned int)kb;
                S.kw[2 * g + 1] = (unsigned int)(kb >> 32);
            }
            if constexpr (first) S.k1 = k; else S.k2 = k;
        }
        __syncthreads();   // kw[2g,2g+1] visible to all
        if constexpr (G1 > g) {
            unsigned int a = getw<2 * g>(S.M1) & S.kw[2 * g];
            unsigned int b = getw<2 * g + 1>(S.M1) & S.kw[2 * g + 1];
            S.sup1 = S.sup1 || ((a | b) != 0u);
        }
        if constexpr (G2 > g) {
            unsigned int a = getw<2 * g>(S.M2) & S.kw[2 * g];
            unsigned int b = getw<2 * g + 1>(S.M2) & S.kw[2 * g + 1];
            S.sup2 = S.sup2 || ((a | b) != 0u);
        }
        sweep_level<g + 1, G1, G2>(S);
    }
}

template<int G1, int G2>
__device__ __forceinline__ void sweep_body(
    float* __restrict__ out, const unsigned int* __restrict__ tmi,
    const float* __restrict__ scores, int img, int lane, unsigned int* kw)
{
    SweepState<G1, G2> S;
    S.M1.load(tmi, lane);
    S.M2.load(tmi, lane);
    const int j1 = G1 * 64 + lane, j2 = G2 * 64 + lane;
    S.v1 = scores[img * P_N + j1] > SCORE_T;
    S.v2 = scores[img * P_N + j2] > SCORE_T;
    S.sup1 = false; S.sup2 = false;
    S.k1 = false;   S.k2 = false;
    S.lane = lane;  S.kw = kw;

    sweep_level<0, G1, G2>(S);

    if (!S.k1) { float* o = out + ((size_t)img * P_N + j1) * 5;
        o[0] = 0.0f; o[1] = 0.0f; o[2] = 0.0f; o[3] = 0.0f; o[4] = 0.0f; }
    if (!S.k2) { float* o = out + ((size_t)img * P_N + j2) * 5;
        o[0] = 0.0f; o[1] = 0.0f; o[2] = 0.0f; o[3] = 0.0f; o[4] = 0.0f; }
}

__global__ __launch_bounds__(1024) void sweep_kernel(
    float* __restrict__ out, const unsigned int* __restrict__ tmask,
    const float* __restrict__ scores)
{
    __shared__ __align__(16) unsigned int kw[64];
    const int img = blockIdx.x, tid = threadIdx.x;
    const int wv = tid >> 6, lane = tid & 63;
    const unsigned int* tmi = tmask + (size_t)img * IMG_TM_U32;
    switch (wv) {
        case  0: sweep_body< 0, 31>(out, tmi, scores, img, lane, kw); break;
        case  1: sweep_body< 1, 30>(out, tmi, scores, img, lane, kw); break;
        case  2: sweep_body< 2, 29>(out, tmi, scores, img, lane, kw); break;
        case  3: sweep_body< 3, 28>(out, tmi, scores, img, lane, kw); break;
        case  4: sweep_body< 4, 27>(out, tmi, scores, img, lane, kw); break;
        case  5: sweep_body< 5, 26>(out, tmi, scores, img, lane, kw); break;
        case  6: sweep_body< 6, 25>(out, tmi, scores, img, lane, kw); break;
        case  7: sweep_body< 7, 24>(out, tmi, scores, img, lane, kw); break;
        case  8: sweep_body< 8, 23>(out, tmi, scores, img, lane, kw); break;
        case  9: sweep_body< 9, 22>(out, tmi, scores, img, lane, kw); break;
        case 10: sweep_body<10, 21>(out, tmi, scores, img, lane, kw); break;
        case 11: sweep_body<11, 20>(out, tmi, scores, img, lane, kw); break;
        case 12: sweep_body<12, 19>(out, tmi, scores, img, lane, kw); break;
        case 13: sweep_body<13, 18>(out, tmi, scores, img, lane, kw); break;
        case 14: sweep_body<14, 17>(out, tmi, scores, img, lane, kw); break;
        case 15: sweep_body<15, 16>(out, tmi, scores, img, lane, kw); break;
    }
}

// ---------------------------------------------------------------------------
// ws-too-small fallback (validated rounds 1-4): bitonic sort + serial cascade
// ---------------------------------------------------------------------------
__global__ __launch_bounds__(1024) void prep_sort_kernel(
    const float* __restrict__ cls, const float* __restrict__ codes,
    const float* __restrict__ props, float* __restrict__ out)
{
#pragma clang fp contract(off)
    __shared__ float4 sbox[P_N];
    __shared__ float  ssc[P_N];
    __shared__ unsigned long long skey[P_N];
    const int img = blockIdx.x;
    const int tid = threadIdx.x;

    for (int p = tid; p < P_N; p += 1024) {
        float4 b; float sc;
        decode_row(cls, codes, props, img * P_N + p, b, sc);
        sbox[p] = b;
        ssc[p]  = sc;
        float key = (sc > SCORE_T) ? -sc : __int_as_float(0x7f800000);
        skey[p] = (((unsigned long long)fkey(key)) << 32) | (unsigned int)p;
    }
    __syncthreads();
    for (int k = 2; k <= P_N; k <<= 1) {
        for (int j = k >> 1; j > 0; j >>= 1) {
            for (int t = tid; t < P_N; t += 1024) {
                int ixj = t ^ j;
                if (ixj > t) {
                    unsigned long long a = skey[t], b = skey[ixj];
                    bool up = ((t & k) == 0);
                    if ((a > b) == up) { skey[t] = b; skey[ixj] = a; }
                }
            }
            __syncthreads();
        }
    }
    for (int e = tid; e < P_N; e += 1024) {
        unsigned long long kv = skey[e];
        int idx = (int)(kv & 0xFFFFFFFFull);
        float4 b4 = sbox[idx];
        float  s  = ssc[idx];
        float* o = out + ((size_t)img * P_N + e) * 5;
        o[0] = b4.x; o[1] = b4.y; o[2] = b4.z; o[3] = b4.w; o[4] = s;
    }
}

__global__ __launch_bounds__(64) void nms_fallback(float* __restrict__ out)
{
#pragma clang fp contract(off)
    __shared__ float4 sb[P_N];
    const int img  = blockIdx.x;
    const int lane = threadIdx.x;
    unsigned int keep = 0;
    for (int b = 0; b < 32; ++b) {
        int p = lane * 32 + b;
        const float* o = out + ((size_t)img * P_N + p) * 5;
        sb[p] = make_float4(o[0], o[1], o[2], o[3]);
        if (o[4] > SCORE_T) keep |= (1u << b);
    }
    __syncthreads();
    for (int i = 0; i < P_N; ++i) {
        unsigned int kw =
            (unsigned int)__builtin_amdgcn_readlane((int)keep, i >> 5);
        if ((kw >> (i & 31)) & 1u) {
            float4 bi = sb[i];
            float area_i = (bi.z - bi.x) * (bi.w - bi.y);
            unsigned int m = 0;
            for (int b = 0; b < 32; ++b) {
                int j = lane * 32 + b;
                if (j > i) {
                    float4 bj = sb[j];
                    float area_j = (bj.z - bj.x) * (bj.w - bj.y);
                    float ltx = fmaxf(bi.x, bj.x);
                    float lty = fmaxf(bi.y, bj.y);
                    float rbx = fminf(bi.z, bj.z);
                    float rby = fminf(bi.w, bj.w);
                    float wx = fmaxf(rbx - ltx, 0.0f);
                    float wy = fmaxf(rby - lty, 0.0f);
                    float inter = wx * wy;
                    float denom = ((area_i + area_j) - inter) + 1e-9f;
                    if ((inter / denom) > 0.5f) m |= (1u << b);
                }
            }
            keep &= ~m;
        }
    }
    for (int b = 0; b < 32; ++b) {
        if (!((keep >> b) & 1u)) {
            int p = lane * 32 + b;
            float* o = out + ((size_t)img * P_N + p) * 5;
            o[0] = 0.0f; o[1] = 0.0f; o[2] = 0.0f; o[3] = 0.0f; o[4] = 0.0f;
        }
    }
}

// ---------------------------------------------------------------------------
extern "C" void kernel_launch(void* const* d_in, const int* in_sizes, int n_in,
                              void* d_out, int out_size, void* d_ws, size_t ws_size,
                              hipStream_t stream) {
    const float* cls   = (const float*)d_in[0];
    const float* codes = (const float*)d_in[1];
    const float* props = (const float*)d_in[2];
    float* out = (float*)d_out;

    const size_t off_tmask  = 0;
    const size_t off_boxes  = off_tmask + (size_t)B_IMG * IMG_TM_U32 * 4; // 4.46 MB
    const size_t off_area   = off_boxes + (size_t)B_IMG * P_N * 16;       // +512 KB
    const size_t off_scores = off_area  + (size_t)B_IMG * P_N * 4;        // +128 KB
    const size_t total      = off_scores + (size_t)B_IMG * P_N * 4;       // +128 KB

    if (ws_size >= total) {
        unsigned int* tmask  = (unsigned int*)((char*)d_ws + off_tmask);
        float4*       boxes4 = (float4*)((char*)d_ws + off_boxes);
        float*        area   = (float*)((char*)d_ws + off_area);
        float*        scores = (float*)((char*)d_ws + off_scores);

        rank_kernel<<<B_IMG * 32, 512, 0, stream>>>(cls, codes, props, out,
                                                    boxes4, area, scores);
        tmask_kernel<<<(B_IMG * TM_TPI) / TM_WPB, 64 * TM_WPB, 0, stream>>>(
            boxes4, area, tmask);
        sweep_kernel<<<B_IMG, 1024, 0, stream>>>(out, tmask, scores);
    } else {
        prep_sort_kernel<<<B_IMG, 1024, 0, stream>>>(cls, codes, props, out);
        nms_fallback<<<B_IMG, 64, 0, stream>>>(out);
    }
}